// Round 1
// baseline (643.294 us; speedup 1.0000x reference)
//
#include <hip/hip_runtime.h>
#include <math.h>

#define N_NODES 50000
#define N_EDGES 800000
#define HID 128
#define N_GRAPHS 128
#define OUTC 10
#define BN_EPS 1e-5f

// ---------------- degree histogram ----------------
__global__ void hist_kernel(const int* __restrict__ src, const int* __restrict__ dst,
                            int* __restrict__ cnt_out, int* __restrict__ cnt_in) {
    int e = blockIdx.x * blockDim.x + threadIdx.x;
    if (e < N_EDGES) {
        atomicAdd(&cnt_out[src[e]], 1);
        atomicAdd(&cnt_in[dst[e]], 1);
    }
}

__global__ void invsqrt_kernel(const int* __restrict__ cnt_out, const int* __restrict__ cnt_in,
                               float* __restrict__ inv_out, float* __restrict__ inv_in) {
    int i = blockIdx.x * blockDim.x + threadIdx.x;
    if (i < N_NODES) {
        inv_out[i] = rsqrtf(fmaxf((float)cnt_out[i], 1.0f));
        inv_in[i]  = rsqrtf(fmaxf((float)cnt_in[i], 1.0f));
    }
}

// ---------------- exclusive scan over in-degrees (single block) ----------------
#define SCAN_T 1024
__global__ void scan_kernel(const int* __restrict__ cnt, int* __restrict__ row_ptr,
                            int* __restrict__ write_off) {
    __shared__ int part[SCAN_T];
    const int CH = (N_NODES + SCAN_T - 1) / SCAN_T;  // 49
    int t = threadIdx.x;
    int beg = t * CH;
    int end = min(beg + CH, N_NODES);
    int s = 0;
    for (int i = beg; i < end; i++) s += cnt[i];
    part[t] = s;
    __syncthreads();
    // Hillis-Steele inclusive scan
    for (int off = 1; off < SCAN_T; off <<= 1) {
        int v = (t >= off) ? part[t - off] : 0;
        __syncthreads();
        part[t] += v;
        __syncthreads();
    }
    int run = (t == 0) ? 0 : part[t - 1];
    for (int i = beg; i < end; i++) {
        row_ptr[i] = run;
        write_off[i] = run;
        run += cnt[i];
    }
    if (t == 0) row_ptr[N_NODES] = part[SCAN_T - 1];
}

// ---------------- CSR fill: edges bucketed by dst, value = src ----------------
__global__ void csr_fill_kernel(const int* __restrict__ src, const int* __restrict__ dst,
                                int* __restrict__ write_off, int* __restrict__ edge_src) {
    int e = blockIdx.x * blockDim.x + threadIdx.x;
    if (e < N_EDGES) {
        int d = dst[e];
        int pos = atomicAdd(&write_off[d], 1);
        edge_src[pos] = src[e];
    }
}

// ---------------- Y[r][:] = (scale[r]*X[r][:]) @ W  (fp32, LDS-tiled) ----------------
// block = 256 threads, tile = 64 rows x 128 cols, thread = 8 rows x 4 cols
__global__ __launch_bounds__(256) void matmul_kernel(const float* __restrict__ X,
                                                     const float* __restrict__ scale,
                                                     const float* __restrict__ W,
                                                     float* __restrict__ Y) {
    __shared__ float xs[64 * HID];   // 32 KB
    __shared__ float wsh[32 * HID];  // 16 KB
    int tid = threadIdx.x;
    int row0 = blockIdx.x * 64;

    // stage X tile with inv_sqrt_out scaling folded in: 8 float4 per thread
    for (int j = 0; j < 8; j++) {
        int idx = (j * 256 + tid) * 4;
        int r = row0 + (idx >> 7);
        float4 v = make_float4(0.f, 0.f, 0.f, 0.f);
        if (r < N_NODES) {
            v = *(const float4*)&X[(size_t)r * HID + (idx & 127)];
            float sc = scale[r];
            v.x *= sc; v.y *= sc; v.z *= sc; v.w *= sc;
        }
        *(float4*)&xs[idx] = v;
    }

    int cx = tid & 31;   // -> cols cx*4 .. cx*4+3
    int ry = tid >> 5;   // -> rows ry*8 .. ry*8+7
    float acc[8][4] = {};

    for (int kt = 0; kt < HID; kt += 32) {
        __syncthreads();   // also guards xs stores on first iteration
        // stage W[kt..kt+31][:] : 4 float4 per thread
        for (int j = 0; j < 4; j++) {
            int idx = (j * 256 + tid) * 4;
            *(float4*)&wsh[idx] = *(const float4*)&W[kt * HID + idx];
        }
        __syncthreads();
        for (int k = 0; k < 32; k += 4) {
            float4 w0 = *(float4*)&wsh[(k + 0) * HID + cx * 4];
            float4 w1 = *(float4*)&wsh[(k + 1) * HID + cx * 4];
            float4 w2 = *(float4*)&wsh[(k + 2) * HID + cx * 4];
            float4 w3 = *(float4*)&wsh[(k + 3) * HID + cx * 4];
#pragma unroll
            for (int i = 0; i < 8; i++) {
                const float4 xv = *(float4*)&xs[(ry * 8 + i) * HID + kt + k];
                acc[i][0] += xv.x * w0.x + xv.y * w1.x + xv.z * w2.x + xv.w * w3.x;
                acc[i][1] += xv.x * w0.y + xv.y * w1.y + xv.z * w2.y + xv.w * w3.y;
                acc[i][2] += xv.x * w0.z + xv.y * w1.z + xv.z * w2.z + xv.w * w3.z;
                acc[i][3] += xv.x * w0.w + xv.y * w1.w + xv.z * w2.w + xv.w * w3.w;
            }
        }
    }

#pragma unroll
    for (int i = 0; i < 8; i++) {
        int r = row0 + ry * 8 + i;
        if (r < N_NODES)
            *(float4*)&Y[(size_t)r * HID + cx * 4] =
                make_float4(acc[i][0], acc[i][1], acc[i][2], acc[i][3]);
    }
}

// ---------------- CSR gather-accumulate: X[n] = relu(inv_in[n]*sum_{e->n} Y[src_e] + b)
// one wave per node, float2 per lane (128 feats / 64 lanes)
__global__ __launch_bounds__(256) void agg_kernel(const float* __restrict__ Y,
                                                  const int* __restrict__ edge_src,
                                                  const int* __restrict__ row_ptr,
                                                  const float* __restrict__ inv_in,
                                                  const float* __restrict__ bias,
                                                  float* __restrict__ Xout) {
    int wave = threadIdx.x >> 6;
    int lane = threadIdx.x & 63;
    int n = blockIdx.x * 4 + wave;
    if (n >= N_NODES) return;
    int beg = row_ptr[n], end = row_ptr[n + 1];
    float ax = 0.f, ay = 0.f;
    for (int base = beg; base < end; base += 64) {
        int cnt = min(64, end - base);
        int idx = (lane < cnt) ? edge_src[base + lane] : 0;
        for (int j = 0; j < cnt; j++) {
            int s = __shfl(idx, j);
            float2 v = *(const float2*)&Y[(size_t)s * HID + lane * 2];
            ax += v.x;
            ay += v.y;
        }
    }
    float si = inv_in[n];
    float2 b = *(const float2*)&bias[lane * 2];
    float2 o = make_float2(fmaxf(ax * si + b.x, 0.f), fmaxf(ay * si + b.y, 0.f));
    *(float2*)&Xout[(size_t)n * HID + lane * 2] = o;
}

// ---------------- SumPooling via sorted graph_ids (binary search bounds) ----------------
__global__ void pool_kernel(const float* __restrict__ X, const int* __restrict__ gid,
                            float* __restrict__ emb) {
    __shared__ int bounds[2];
    int g = blockIdx.x;
    int t = threadIdx.x;  // 128
    if (t < 2) {
        int target = g + t;  // lower_bound(gid, target)
        int lo = 0, hi = N_NODES;
        while (lo < hi) {
            int mid = (lo + hi) >> 1;
            if (gid[mid] < target) lo = mid + 1; else hi = mid;
        }
        bounds[t] = lo;
    }
    __syncthreads();
    int beg = bounds[0], end = bounds[1];
    float s = 0.f;
    for (int n = beg; n < end; n++) s += X[(size_t)n * HID + t];
    emb[g * HID + t] = s;
}

// ---------------- BatchNorm batch stats -> per-feature scale/shift ----------------
__global__ void bnstats_kernel(const float* __restrict__ emb, const float* __restrict__ gamma,
                               const float* __restrict__ beta, float* __restrict__ scale,
                               float* __restrict__ shift) {
    int f = threadIdx.x;  // 128
    float s = 0.f;
    for (int r = 0; r < N_GRAPHS; r++) s += emb[r * HID + f];
    float mu = s * (1.f / N_GRAPHS);
    float v = 0.f;
    for (int r = 0; r < N_GRAPHS; r++) {
        float d = emb[r * HID + f] - mu;
        v += d * d;
    }
    v *= (1.f / N_GRAPHS);
    float sc = gamma[f] * rsqrtf(v + BN_EPS);
    scale[f] = sc;
    shift[f] = beta[f] - mu * sc;
}

// ---------------- fc1: H = relu(bn(emb) @ fc1_w + fc1_b) ----------------
__global__ void fc1_kernel(const float* __restrict__ emb, const float* __restrict__ scale,
                           const float* __restrict__ shift, const float* __restrict__ W,
                           const float* __restrict__ b, float* __restrict__ H) {
    __shared__ float xr[HID];
    int r = blockIdx.x, c = threadIdx.x;  // 128 threads
    xr[c] = emb[r * HID + c] * scale[c] + shift[c];
    __syncthreads();
    float acc = b[c];
    for (int k = 0; k < HID; k++) acc += xr[k] * W[k * HID + c];
    H[r * HID + c] = fmaxf(acc, 0.f);
}

// ---------------- fc2 + log_softmax ----------------
__global__ void head_kernel(const float* __restrict__ H, const float* __restrict__ W,
                            const float* __restrict__ b, float* __restrict__ out) {
    __shared__ float hr[HID];
    __shared__ float logits[OUTC];
    __shared__ float mstat[2];
    int r = blockIdx.x, t = threadIdx.x;  // 64 threads
    hr[t] = H[r * HID + t];
    hr[t + 64] = H[r * HID + t + 64];
    __syncthreads();
    if (t < OUTC) {
        float acc = b[t];
        for (int k = 0; k < HID; k++) acc += hr[k] * W[k * OUTC + t];
        logits[t] = acc;
    }
    __syncthreads();
    if (t == 0) {
        float m = logits[0];
        for (int o = 1; o < OUTC; o++) m = fmaxf(m, logits[o]);
        float sum = 0.f;
        for (int o = 0; o < OUTC; o++) sum += expf(logits[o] - m);
        mstat[0] = m;
        mstat[1] = logf(sum);
    }
    __syncthreads();
    if (t < OUTC) out[r * OUTC + t] = logits[t] - mstat[0] - mstat[1];
}

extern "C" void kernel_launch(void* const* d_in, const int* in_sizes, int n_in,
                              void* d_out, int out_size, void* d_ws, size_t ws_size,
                              hipStream_t stream) {
    const float* n_feat = (const float*)d_in[0];
    const int*   src    = (const int*)d_in[1];
    const int*   dst    = (const int*)d_in[2];
    const int*   gid    = (const int*)d_in[3];
    const float* W1     = (const float*)d_in[4];
    const float* b1     = (const float*)d_in[5];
    const float* W2     = (const float*)d_in[6];
    const float* b2     = (const float*)d_in[7];
    const float* gamma  = (const float*)d_in[8];
    const float* beta   = (const float*)d_in[9];
    const float* fc1_w  = (const float*)d_in[10];
    const float* fc1_b  = (const float*)d_in[11];
    const float* fc2_w  = (const float*)d_in[12];
    const float* fc2_b  = (const float*)d_in[13];

    char* wsb = (char*)d_ws;
    size_t off = 0;
    auto alloc = [&](size_t bytes) -> void* {
        void* p = wsb + off;
        off += (bytes + 255) & ~(size_t)255;
        return p;
    };
    int*   cnt_out = (int*)alloc((size_t)N_NODES * 4);
    int*   cnt_in  = (int*)alloc((size_t)N_NODES * 4);
    int*   row_ptr = (int*)alloc((size_t)(N_NODES + 1) * 4);
    int*   wr_off  = (int*)alloc((size_t)(N_NODES + 1) * 4);
    int*   e_src   = (int*)alloc((size_t)N_EDGES * 4);
    float* inv_out = (float*)alloc((size_t)N_NODES * 4);
    float* inv_in  = (float*)alloc((size_t)N_NODES * 4);
    float* Y       = (float*)alloc((size_t)N_NODES * HID * 4);
    float* X       = (float*)alloc((size_t)N_NODES * HID * 4);
    float* scale   = (float*)alloc(HID * 4);
    float* shift   = (float*)alloc(HID * 4);
    float* H       = (float*)alloc((size_t)N_GRAPHS * HID * 4);

    float* emb_out = (float*)d_out;                // [128,128]
    float* lsm_out = emb_out + N_GRAPHS * HID;     // [128,10]

    hipMemsetAsync(cnt_out, 0, (size_t)N_NODES * 4, stream);
    hipMemsetAsync(cnt_in,  0, (size_t)N_NODES * 4, stream);

    hist_kernel<<<(N_EDGES + 255) / 256, 256, 0, stream>>>(src, dst, cnt_out, cnt_in);
    invsqrt_kernel<<<(N_NODES + 255) / 256, 256, 0, stream>>>(cnt_out, cnt_in, inv_out, inv_in);
    scan_kernel<<<1, SCAN_T, 0, stream>>>(cnt_in, row_ptr, wr_off);
    csr_fill_kernel<<<(N_EDGES + 255) / 256, 256, 0, stream>>>(src, dst, wr_off, e_src);

    // layer 1
    matmul_kernel<<<(N_NODES + 63) / 64, 256, 0, stream>>>(n_feat, inv_out, W1, Y);
    agg_kernel<<<(N_NODES + 3) / 4, 256, 0, stream>>>(Y, e_src, row_ptr, inv_in, b1, X);
    // layer 2
    matmul_kernel<<<(N_NODES + 63) / 64, 256, 0, stream>>>(X, inv_out, W2, Y);
    agg_kernel<<<(N_NODES + 3) / 4, 256, 0, stream>>>(Y, e_src, row_ptr, inv_in, b2, X);

    // pooling -> embedding output
    pool_kernel<<<N_GRAPHS, HID, 0, stream>>>(X, gid, emb_out);
    // head
    bnstats_kernel<<<1, HID, 0, stream>>>(emb_out, gamma, beta, scale, shift);
    fc1_kernel<<<N_GRAPHS, HID, 0, stream>>>(emb_out, scale, shift, fc1_w, fc1_b, H);
    head_kernel<<<N_GRAPHS, 64, 0, stream>>>(H, fc2_w, fc2_b, lsm_out);
}

// Round 2
// 544.017 us; speedup vs baseline: 1.1825x; 1.1825x over previous
//
#include <hip/hip_runtime.h>
#include <math.h>

#define N_NODES 50000
#define N_EDGES 800000
#define HID 128
#define N_GRAPHS 128
#define OUTC 10
#define BN_EPS 1e-5f

#define SCAN_B 256
#define N_SCAN_BLOCKS ((N_NODES + SCAN_B - 1) / SCAN_B)  // 196

// ---------------- degree histogram ----------------
__global__ void hist_kernel(const int* __restrict__ src, const int* __restrict__ dst,
                            int* __restrict__ cnt_out, int* __restrict__ cnt_in) {
    int e = blockIdx.x * blockDim.x + threadIdx.x;
    if (e < N_EDGES) {
        atomicAdd(&cnt_out[src[e]], 1);
        atomicAdd(&cnt_in[dst[e]], 1);
    }
}

__global__ void invsqrt_kernel(const int* __restrict__ cnt_out, const int* __restrict__ cnt_in,
                               float* __restrict__ inv_out, float* __restrict__ inv_in) {
    int i = blockIdx.x * blockDim.x + threadIdx.x;
    if (i < N_NODES) {
        inv_out[i] = rsqrtf(fmaxf((float)cnt_out[i], 1.0f));
        inv_in[i]  = rsqrtf(fmaxf((float)cnt_in[i], 1.0f));
    }
}

// ---------------- 3-phase exclusive scan over in-degrees ----------------
// Phase 1: per-256-chunk sums (wave shuffle reduce)
__global__ void scan_sum_kernel(const int* __restrict__ cnt, int* __restrict__ bsum) {
    int i = blockIdx.x * SCAN_B + threadIdx.x;
    int v = (i < N_NODES) ? cnt[i] : 0;
#pragma unroll
    for (int o = 32; o > 0; o >>= 1) v += __shfl_down(v, o);
    __shared__ int ws[4];
    int wave = threadIdx.x >> 6, lane = threadIdx.x & 63;
    if (lane == 0) ws[wave] = v;
    __syncthreads();
    if (threadIdx.x == 0) bsum[blockIdx.x] = ws[0] + ws[1] + ws[2] + ws[3];
}

// Phase 2: single block scans the 196 block sums in LDS -> exclusive block offsets
__global__ void scan_bsum_kernel(const int* __restrict__ bsum, int* __restrict__ boff) {
    __shared__ int part[SCAN_B];
    int t = threadIdx.x;
    int v = (t < N_SCAN_BLOCKS) ? bsum[t] : 0;
    part[t] = v;
    __syncthreads();
    for (int off = 1; off < SCAN_B; off <<= 1) {
        int u = (t >= off) ? part[t - off] : 0;
        __syncthreads();
        part[t] += u;
        __syncthreads();
    }
    boff[t] = part[t] - v;  // exclusive prefix of block sums
}

// Phase 3: in-block scan of each chunk + block offset -> row_ptr / write_off
__global__ void scan_write_kernel(const int* __restrict__ cnt, const int* __restrict__ boff,
                                  int* __restrict__ row_ptr, int* __restrict__ wr_off) {
    __shared__ int part[SCAN_B];
    int t = threadIdx.x;
    int i = blockIdx.x * SCAN_B + t;
    int v = (i < N_NODES) ? cnt[i] : 0;
    part[t] = v;
    __syncthreads();
    for (int off = 1; off < SCAN_B; off <<= 1) {
        int u = (t >= off) ? part[t - off] : 0;
        __syncthreads();
        part[t] += u;
        __syncthreads();
    }
    if (i < N_NODES) {
        int ex = part[t] - v + boff[blockIdx.x];
        row_ptr[i] = ex;
        wr_off[i] = ex;
    }
    if (i == 0) row_ptr[N_NODES] = N_EDGES;  // total in-degree is exactly N_EDGES
}

// ---------------- CSR fill: edges bucketed by dst, value = src ----------------
__global__ void csr_fill_kernel(const int* __restrict__ src, const int* __restrict__ dst,
                                int* __restrict__ write_off, int* __restrict__ edge_src) {
    int e = blockIdx.x * blockDim.x + threadIdx.x;
    if (e < N_EDGES) {
        int d = dst[e];
        int pos = atomicAdd(&write_off[d], 1);
        edge_src[pos] = src[e];
    }
}

// ---------------- Y[r][:] = (scale[r]*X[r][:]) @ W  (fp32, LDS-tiled) ----------------
// block = 256 threads, tile = 64 rows x 128 cols, thread = 8 rows x 4 cols
__global__ __launch_bounds__(256) void matmul_kernel(const float* __restrict__ X,
                                                     const float* __restrict__ scale,
                                                     const float* __restrict__ W,
                                                     float* __restrict__ Y) {
    __shared__ float xs[64 * HID];   // 32 KB
    __shared__ float wsh[32 * HID];  // 16 KB
    int tid = threadIdx.x;
    int row0 = blockIdx.x * 64;

    // stage X tile with inv_sqrt_out scaling folded in: 8 float4 per thread
    for (int j = 0; j < 8; j++) {
        int idx = (j * 256 + tid) * 4;
        int r = row0 + (idx >> 7);
        float4 v = make_float4(0.f, 0.f, 0.f, 0.f);
        if (r < N_NODES) {
            v = *(const float4*)&X[(size_t)r * HID + (idx & 127)];
            float sc = scale[r];
            v.x *= sc; v.y *= sc; v.z *= sc; v.w *= sc;
        }
        *(float4*)&xs[idx] = v;
    }

    int cx = tid & 31;   // -> cols cx*4 .. cx*4+3
    int ry = tid >> 5;   // -> rows ry*8 .. ry*8+7
    float acc[8][4] = {};

    for (int kt = 0; kt < HID; kt += 32) {
        __syncthreads();   // also guards xs stores on first iteration
        // stage W[kt..kt+31][:] : 4 float4 per thread
        for (int j = 0; j < 4; j++) {
            int idx = (j * 256 + tid) * 4;
            *(float4*)&wsh[idx] = *(const float4*)&W[kt * HID + idx];
        }
        __syncthreads();
        for (int k = 0; k < 32; k += 4) {
            float4 w0 = *(float4*)&wsh[(k + 0) * HID + cx * 4];
            float4 w1 = *(float4*)&wsh[(k + 1) * HID + cx * 4];
            float4 w2 = *(float4*)&wsh[(k + 2) * HID + cx * 4];
            float4 w3 = *(float4*)&wsh[(k + 3) * HID + cx * 4];
#pragma unroll
            for (int i = 0; i < 8; i++) {
                const float4 xv = *(float4*)&xs[(ry * 8 + i) * HID + kt + k];
                acc[i][0] += xv.x * w0.x + xv.y * w1.x + xv.z * w2.x + xv.w * w3.x;
                acc[i][1] += xv.x * w0.y + xv.y * w1.y + xv.z * w2.y + xv.w * w3.y;
                acc[i][2] += xv.x * w0.z + xv.y * w1.z + xv.z * w2.z + xv.w * w3.z;
                acc[i][3] += xv.x * w0.w + xv.y * w1.w + xv.z * w2.w + xv.w * w3.w;
            }
        }
    }

#pragma unroll
    for (int i = 0; i < 8; i++) {
        int r = row0 + ry * 8 + i;
        if (r < N_NODES)
            *(float4*)&Y[(size_t)r * HID + cx * 4] =
                make_float4(acc[i][0], acc[i][1], acc[i][2], acc[i][3]);
    }
}

// ---------------- CSR gather-accumulate: X[n] = relu(inv_in[n]*sum_{e->n} Y[src_e] + b)
// one wave per node, float2 per lane (128 feats / 64 lanes)
__global__ __launch_bounds__(256) void agg_kernel(const float* __restrict__ Y,
                                                  const int* __restrict__ edge_src,
                                                  const int* __restrict__ row_ptr,
                                                  const float* __restrict__ inv_in,
                                                  const float* __restrict__ bias,
                                                  float* __restrict__ Xout) {
    int wave = threadIdx.x >> 6;
    int lane = threadIdx.x & 63;
    int n = blockIdx.x * 4 + wave;
    if (n >= N_NODES) return;
    int beg = row_ptr[n], end = row_ptr[n + 1];
    float ax = 0.f, ay = 0.f;
    for (int base = beg; base < end; base += 64) {
        int cnt = min(64, end - base);
        int idx = (lane < cnt) ? edge_src[base + lane] : 0;
        for (int j = 0; j < cnt; j++) {
            int s = __shfl(idx, j);
            float2 v = *(const float2*)&Y[(size_t)s * HID + lane * 2];
            ax += v.x;
            ay += v.y;
        }
    }
    float si = inv_in[n];
    float2 b = *(const float2*)&bias[lane * 2];
    float2 o = make_float2(fmaxf(ax * si + b.x, 0.f), fmaxf(ay * si + b.y, 0.f));
    *(float2*)&Xout[(size_t)n * HID + lane * 2] = o;
}

// ---------------- SumPooling via sorted graph_ids (binary search bounds) ----------------
__global__ void pool_kernel(const float* __restrict__ X, const int* __restrict__ gid,
                            float* __restrict__ emb) {
    __shared__ int bounds[2];
    int g = blockIdx.x;
    int t = threadIdx.x;  // 128
    if (t < 2) {
        int target = g + t;  // lower_bound(gid, target)
        int lo = 0, hi = N_NODES;
        while (lo < hi) {
            int mid = (lo + hi) >> 1;
            if (gid[mid] < target) lo = mid + 1; else hi = mid;
        }
        bounds[t] = lo;
    }
    __syncthreads();
    int beg = bounds[0], end = bounds[1];
    float s = 0.f;
    for (int n = beg; n < end; n++) s += X[(size_t)n * HID + t];
    emb[g * HID + t] = s;
}

// ---------------- BatchNorm batch stats -> per-feature scale/shift ----------------
__global__ void bnstats_kernel(const float* __restrict__ emb, const float* __restrict__ gamma,
                               const float* __restrict__ beta, float* __restrict__ scale,
                               float* __restrict__ shift) {
    int f = threadIdx.x;  // 128
    float s = 0.f;
    for (int r = 0; r < N_GRAPHS; r++) s += emb[r * HID + f];
    float mu = s * (1.f / N_GRAPHS);
    float v = 0.f;
    for (int r = 0; r < N_GRAPHS; r++) {
        float d = emb[r * HID + f] - mu;
        v += d * d;
    }
    v *= (1.f / N_GRAPHS);
    float sc = gamma[f] * rsqrtf(v + BN_EPS);
    scale[f] = sc;
    shift[f] = beta[f] - mu * sc;
}

// ---------------- fc1: H = relu(bn(emb) @ fc1_w + fc1_b) ----------------
__global__ void fc1_kernel(const float* __restrict__ emb, const float* __restrict__ scale,
                           const float* __restrict__ shift, const float* __restrict__ W,
                           const float* __restrict__ b, float* __restrict__ H) {
    __shared__ float xr[HID];
    int r = blockIdx.x, c = threadIdx.x;  // 128 threads
    xr[c] = emb[r * HID + c] * scale[c] + shift[c];
    __syncthreads();
    float acc = b[c];
    for (int k = 0; k < HID; k++) acc += xr[k] * W[k * HID + c];
    H[r * HID + c] = fmaxf(acc, 0.f);
}

// ---------------- fc2 + log_softmax ----------------
__global__ void head_kernel(const float* __restrict__ H, const float* __restrict__ W,
                            const float* __restrict__ b, float* __restrict__ out) {
    __shared__ float hr[HID];
    __shared__ float logits[OUTC];
    __shared__ float mstat[2];
    int r = blockIdx.x, t = threadIdx.x;  // 64 threads
    hr[t] = H[r * HID + t];
    hr[t + 64] = H[r * HID + t + 64];
    __syncthreads();
    if (t < OUTC) {
        float acc = b[t];
        for (int k = 0; k < HID; k++) acc += hr[k] * W[k * OUTC + t];
        logits[t] = acc;
    }
    __syncthreads();
    if (t == 0) {
        float m = logits[0];
        for (int o = 1; o < OUTC; o++) m = fmaxf(m, logits[o]);
        float sum = 0.f;
        for (int o = 0; o < OUTC; o++) sum += expf(logits[o] - m);
        mstat[0] = m;
        mstat[1] = logf(sum);
    }
    __syncthreads();
    if (t < OUTC) out[r * OUTC + t] = logits[t] - mstat[0] - mstat[1];
}

extern "C" void kernel_launch(void* const* d_in, const int* in_sizes, int n_in,
                              void* d_out, int out_size, void* d_ws, size_t ws_size,
                              hipStream_t stream) {
    const float* n_feat = (const float*)d_in[0];
    const int*   src    = (const int*)d_in[1];
    const int*   dst    = (const int*)d_in[2];
    const int*   gid    = (const int*)d_in[3];
    const float* W1     = (const float*)d_in[4];
    const float* b1     = (const float*)d_in[5];
    const float* W2     = (const float*)d_in[6];
    const float* b2     = (const float*)d_in[7];
    const float* gamma  = (const float*)d_in[8];
    const float* beta   = (const float*)d_in[9];
    const float* fc1_w  = (const float*)d_in[10];
    const float* fc1_b  = (const float*)d_in[11];
    const float* fc2_w  = (const float*)d_in[12];
    const float* fc2_b  = (const float*)d_in[13];

    char* wsb = (char*)d_ws;
    size_t off = 0;
    auto alloc = [&](size_t bytes) -> void* {
        void* p = wsb + off;
        off += (bytes + 255) & ~(size_t)255;
        return p;
    };
    int*   cnt_out = (int*)alloc((size_t)N_NODES * 4);
    int*   cnt_in  = (int*)alloc((size_t)N_NODES * 4);
    int*   row_ptr = (int*)alloc((size_t)(N_NODES + 1) * 4);
    int*   wr_off  = (int*)alloc((size_t)(N_NODES + 1) * 4);
    int*   e_src   = (int*)alloc((size_t)N_EDGES * 4);
    float* inv_out = (float*)alloc((size_t)N_NODES * 4);
    float* inv_in  = (float*)alloc((size_t)N_NODES * 4);
    float* Y       = (float*)alloc((size_t)N_NODES * HID * 4);
    float* X       = (float*)alloc((size_t)N_NODES * HID * 4);
    float* scale   = (float*)alloc(HID * 4);
    float* shift   = (float*)alloc(HID * 4);
    float* H       = (float*)alloc((size_t)N_GRAPHS * HID * 4);
    int*   bsum    = (int*)alloc((size_t)SCAN_B * 4);
    int*   boff    = (int*)alloc((size_t)SCAN_B * 4);

    float* emb_out = (float*)d_out;                // [128,128]
    float* lsm_out = emb_out + N_GRAPHS * HID;     // [128,10]

    hipMemsetAsync(cnt_out, 0, (size_t)N_NODES * 4, stream);
    hipMemsetAsync(cnt_in,  0, (size_t)N_NODES * 4, stream);

    hist_kernel<<<(N_EDGES + 255) / 256, 256, 0, stream>>>(src, dst, cnt_out, cnt_in);
    invsqrt_kernel<<<(N_NODES + 255) / 256, 256, 0, stream>>>(cnt_out, cnt_in, inv_out, inv_in);
    scan_sum_kernel<<<N_SCAN_BLOCKS, SCAN_B, 0, stream>>>(cnt_in, bsum);
    scan_bsum_kernel<<<1, SCAN_B, 0, stream>>>(bsum, boff);
    scan_write_kernel<<<N_SCAN_BLOCKS, SCAN_B, 0, stream>>>(cnt_in, boff, row_ptr, wr_off);
    csr_fill_kernel<<<(N_EDGES + 255) / 256, 256, 0, stream>>>(src, dst, wr_off, e_src);

    // layer 1
    matmul_kernel<<<(N_NODES + 63) / 64, 256, 0, stream>>>(n_feat, inv_out, W1, Y);
    agg_kernel<<<(N_NODES + 3) / 4, 256, 0, stream>>>(Y, e_src, row_ptr, inv_in, b1, X);
    // layer 2
    matmul_kernel<<<(N_NODES + 63) / 64, 256, 0, stream>>>(X, inv_out, W2, Y);
    agg_kernel<<<(N_NODES + 3) / 4, 256, 0, stream>>>(Y, e_src, row_ptr, inv_in, b2, X);

    // pooling -> embedding output
    pool_kernel<<<N_GRAPHS, HID, 0, stream>>>(X, gid, emb_out);
    // head
    bnstats_kernel<<<1, HID, 0, stream>>>(emb_out, gamma, beta, scale, shift);
    fc1_kernel<<<N_GRAPHS, HID, 0, stream>>>(emb_out, scale, shift, fc1_w, fc1_b, H);
    head_kernel<<<N_GRAPHS, 64, 0, stream>>>(H, fc2_w, fc2_b, lsm_out);
}

// Round 3
// 450.740 us; speedup vs baseline: 1.4272x; 1.2069x over previous
//
#include <hip/hip_runtime.h>
#include <math.h>

#define N_NODES 50000
#define N_EDGES 800000
#define HID 128
#define N_GRAPHS 128
#define OUTC 10
#define BN_EPS 1e-5f

#define SCAN_B 256
#define N_SCAN_BLOCKS ((N_NODES + SCAN_B - 1) / SCAN_B)  // 196

#define POOL_CHUNK 32
#define N_POOL_BLOCKS ((N_NODES + POOL_CHUNK - 1) / POOL_CHUNK)  // 1563

// ---------------- degree histogram ----------------
__global__ void hist_kernel(const int* __restrict__ src, const int* __restrict__ dst,
                            int* __restrict__ cnt_out, int* __restrict__ cnt_in) {
    int e = blockIdx.x * blockDim.x + threadIdx.x;
    if (e < N_EDGES) {
        atomicAdd(&cnt_out[src[e]], 1);
        atomicAdd(&cnt_in[dst[e]], 1);
    }
}

__global__ void invsqrt_kernel(const int* __restrict__ cnt_out, const int* __restrict__ cnt_in,
                               float* __restrict__ inv_out, float* __restrict__ inv_in) {
    int i = blockIdx.x * blockDim.x + threadIdx.x;
    if (i < N_NODES) {
        inv_out[i] = rsqrtf(fmaxf((float)cnt_out[i], 1.0f));
        inv_in[i]  = rsqrtf(fmaxf((float)cnt_in[i], 1.0f));
    }
}

// ---------------- 3-phase exclusive scan over in-degrees ----------------
__global__ void scan_sum_kernel(const int* __restrict__ cnt, int* __restrict__ bsum) {
    int i = blockIdx.x * SCAN_B + threadIdx.x;
    int v = (i < N_NODES) ? cnt[i] : 0;
#pragma unroll
    for (int o = 32; o > 0; o >>= 1) v += __shfl_down(v, o);
    __shared__ int ws[4];
    int wave = threadIdx.x >> 6, lane = threadIdx.x & 63;
    if (lane == 0) ws[wave] = v;
    __syncthreads();
    if (threadIdx.x == 0) bsum[blockIdx.x] = ws[0] + ws[1] + ws[2] + ws[3];
}

__global__ void scan_bsum_kernel(const int* __restrict__ bsum, int* __restrict__ boff) {
    __shared__ int part[SCAN_B];
    int t = threadIdx.x;
    int v = (t < N_SCAN_BLOCKS) ? bsum[t] : 0;
    part[t] = v;
    __syncthreads();
    for (int off = 1; off < SCAN_B; off <<= 1) {
        int u = (t >= off) ? part[t - off] : 0;
        __syncthreads();
        part[t] += u;
        __syncthreads();
    }
    boff[t] = part[t] - v;  // exclusive prefix of block sums
}

__global__ void scan_write_kernel(const int* __restrict__ cnt, const int* __restrict__ boff,
                                  int* __restrict__ row_ptr, int* __restrict__ wr_off) {
    __shared__ int part[SCAN_B];
    int t = threadIdx.x;
    int i = blockIdx.x * SCAN_B + t;
    int v = (i < N_NODES) ? cnt[i] : 0;
    part[t] = v;
    __syncthreads();
    for (int off = 1; off < SCAN_B; off <<= 1) {
        int u = (t >= off) ? part[t - off] : 0;
        __syncthreads();
        part[t] += u;
        __syncthreads();
    }
    if (i < N_NODES) {
        int ex = part[t] - v + boff[blockIdx.x];
        row_ptr[i] = ex;
        wr_off[i] = ex;
    }
    if (i == 0) row_ptr[N_NODES] = N_EDGES;
}

// ---------------- CSR fill: edges bucketed by dst, value = src ----------------
__global__ void csr_fill_kernel(const int* __restrict__ src, const int* __restrict__ dst,
                                int* __restrict__ write_off, int* __restrict__ edge_src) {
    int e = blockIdx.x * blockDim.x + threadIdx.x;
    if (e < N_EDGES) {
        int d = dst[e];
        int pos = atomicAdd(&write_off[d], 1);
        edge_src[pos] = src[e];
    }
}

// ---------------- Y[r][:] = (scale[r]*X[r][:]) @ W  (fp32, LDS-tiled) ----------------
__global__ __launch_bounds__(256) void matmul_kernel(const float* __restrict__ X,
                                                     const float* __restrict__ scale,
                                                     const float* __restrict__ W,
                                                     float* __restrict__ Y) {
    __shared__ float xs[64 * HID];   // 32 KB
    __shared__ float wsh[32 * HID];  // 16 KB
    int tid = threadIdx.x;
    int row0 = blockIdx.x * 64;

    for (int j = 0; j < 8; j++) {
        int idx = (j * 256 + tid) * 4;
        int r = row0 + (idx >> 7);
        float4 v = make_float4(0.f, 0.f, 0.f, 0.f);
        if (r < N_NODES) {
            v = *(const float4*)&X[(size_t)r * HID + (idx & 127)];
            float sc = scale[r];
            v.x *= sc; v.y *= sc; v.z *= sc; v.w *= sc;
        }
        *(float4*)&xs[idx] = v;
    }

    int cx = tid & 31;
    int ry = tid >> 5;
    float acc[8][4] = {};

    for (int kt = 0; kt < HID; kt += 32) {
        __syncthreads();
        for (int j = 0; j < 4; j++) {
            int idx = (j * 256 + tid) * 4;
            *(float4*)&wsh[idx] = *(const float4*)&W[kt * HID + idx];
        }
        __syncthreads();
        for (int k = 0; k < 32; k += 4) {
            float4 w0 = *(float4*)&wsh[(k + 0) * HID + cx * 4];
            float4 w1 = *(float4*)&wsh[(k + 1) * HID + cx * 4];
            float4 w2 = *(float4*)&wsh[(k + 2) * HID + cx * 4];
            float4 w3 = *(float4*)&wsh[(k + 3) * HID + cx * 4];
#pragma unroll
            for (int i = 0; i < 8; i++) {
                const float4 xv = *(float4*)&xs[(ry * 8 + i) * HID + kt + k];
                acc[i][0] += xv.x * w0.x + xv.y * w1.x + xv.z * w2.x + xv.w * w3.x;
                acc[i][1] += xv.x * w0.y + xv.y * w1.y + xv.z * w2.y + xv.w * w3.y;
                acc[i][2] += xv.x * w0.z + xv.y * w1.z + xv.z * w2.z + xv.w * w3.z;
                acc[i][3] += xv.x * w0.w + xv.y * w1.w + xv.z * w2.w + xv.w * w3.w;
            }
        }
    }

#pragma unroll
    for (int i = 0; i < 8; i++) {
        int r = row0 + ry * 8 + i;
        if (r < N_NODES)
            *(float4*)&Y[(size_t)r * HID + cx * 4] =
                make_float4(acc[i][0], acc[i][1], acc[i][2], acc[i][3]);
    }
}

// ---------------- CSR gather-accumulate ----------------
__global__ __launch_bounds__(256) void agg_kernel(const float* __restrict__ Y,
                                                  const int* __restrict__ edge_src,
                                                  const int* __restrict__ row_ptr,
                                                  const float* __restrict__ inv_in,
                                                  const float* __restrict__ bias,
                                                  float* __restrict__ Xout) {
    int wave = threadIdx.x >> 6;
    int lane = threadIdx.x & 63;
    int n = blockIdx.x * 4 + wave;
    if (n >= N_NODES) return;
    int beg = row_ptr[n], end = row_ptr[n + 1];
    float ax = 0.f, ay = 0.f;
    for (int base = beg; base < end; base += 64) {
        int cnt = min(64, end - base);
        int idx = (lane < cnt) ? edge_src[base + lane] : 0;
        for (int j = 0; j < cnt; j++) {
            int s = __shfl(idx, j);
            float2 v = *(const float2*)&Y[(size_t)s * HID + lane * 2];
            ax += v.x;
            ay += v.y;
        }
    }
    float si = inv_in[n];
    float2 b = *(const float2*)&bias[lane * 2];
    float2 o = make_float2(fmaxf(ax * si + b.x, 0.f), fmaxf(ay * si + b.y, 0.f));
    *(float2*)&Xout[(size_t)n * HID + lane * 2] = o;
}

// ---------------- SumPooling: chunked segment-sum over sorted gid ----------------
// 1563 blocks x 1 wave; float2/lane; atomic flush only at segment boundaries.
__global__ __launch_bounds__(64) void pool_kernel(const float* __restrict__ X,
                                                  const int* __restrict__ gid,
                                                  float* __restrict__ emb) {
    int lane = threadIdx.x;  // 64, feature pair lane*2, lane*2+1
    int n0 = blockIdx.x * POOL_CHUNK;
    int n1 = min(n0 + POOL_CHUNK, N_NODES);
    if (n0 >= N_NODES) return;
    int g_cur = gid[n0];
    float ax = 0.f, ay = 0.f;
    for (int n = n0; n < n1; n++) {
        int g = gid[n];  // same-address broadcast per wave
        if (g != g_cur) {  // wave-uniform branch
            atomicAdd(&emb[g_cur * HID + lane * 2], ax);
            atomicAdd(&emb[g_cur * HID + lane * 2 + 1], ay);
            ax = 0.f; ay = 0.f;
            g_cur = g;
        }
        float2 v = *(const float2*)&X[(size_t)n * HID + lane * 2];
        ax += v.x;
        ay += v.y;
    }
    atomicAdd(&emb[g_cur * HID + lane * 2], ax);
    atomicAdd(&emb[g_cur * HID + lane * 2 + 1], ay);
}

// ---------------- BatchNorm batch stats -> per-feature scale/shift ----------------
__global__ void bnstats_kernel(const float* __restrict__ emb, const float* __restrict__ gamma,
                               const float* __restrict__ beta, float* __restrict__ scale,
                               float* __restrict__ shift) {
    int f = threadIdx.x;  // 128
    float s = 0.f;
    for (int r = 0; r < N_GRAPHS; r++) s += emb[r * HID + f];
    float mu = s * (1.f / N_GRAPHS);
    float v = 0.f;
    for (int r = 0; r < N_GRAPHS; r++) {
        float d = emb[r * HID + f] - mu;
        v += d * d;
    }
    v *= (1.f / N_GRAPHS);
    float sc = gamma[f] * rsqrtf(v + BN_EPS);
    scale[f] = sc;
    shift[f] = beta[f] - mu * sc;
}

// ---------------- fc1 ----------------
__global__ void fc1_kernel(const float* __restrict__ emb, const float* __restrict__ scale,
                           const float* __restrict__ shift, const float* __restrict__ W,
                           const float* __restrict__ b, float* __restrict__ H) {
    __shared__ float xr[HID];
    int r = blockIdx.x, c = threadIdx.x;  // 128 threads
    xr[c] = emb[r * HID + c] * scale[c] + shift[c];
    __syncthreads();
    float acc = b[c];
    for (int k = 0; k < HID; k++) acc += xr[k] * W[k * HID + c];
    H[r * HID + c] = fmaxf(acc, 0.f);
}

// ---------------- fc2 + log_softmax ----------------
__global__ void head_kernel(const float* __restrict__ H, const float* __restrict__ W,
                            const float* __restrict__ b, float* __restrict__ out) {
    __shared__ float hr[HID];
    __shared__ float logits[OUTC];
    __shared__ float mstat[2];
    int r = blockIdx.x, t = threadIdx.x;  // 64 threads
    hr[t] = H[r * HID + t];
    hr[t + 64] = H[r * HID + t + 64];
    __syncthreads();
    if (t < OUTC) {
        float acc = b[t];
        for (int k = 0; k < HID; k++) acc += hr[k] * W[k * OUTC + t];
        logits[t] = acc;
    }
    __syncthreads();
    if (t == 0) {
        float m = logits[0];
        for (int o = 1; o < OUTC; o++) m = fmaxf(m, logits[o]);
        float sum = 0.f;
        for (int o = 0; o < OUTC; o++) sum += expf(logits[o] - m);
        mstat[0] = m;
        mstat[1] = logf(sum);
    }
    __syncthreads();
    if (t < OUTC) out[r * OUTC + t] = logits[t] - mstat[0] - mstat[1];
}

extern "C" void kernel_launch(void* const* d_in, const int* in_sizes, int n_in,
                              void* d_out, int out_size, void* d_ws, size_t ws_size,
                              hipStream_t stream) {
    const float* n_feat = (const float*)d_in[0];
    const int*   src    = (const int*)d_in[1];
    const int*   dst    = (const int*)d_in[2];
    const int*   gid    = (const int*)d_in[3];
    const float* W1     = (const float*)d_in[4];
    const float* b1     = (const float*)d_in[5];
    const float* W2     = (const float*)d_in[6];
    const float* b2     = (const float*)d_in[7];
    const float* gamma  = (const float*)d_in[8];
    const float* beta   = (const float*)d_in[9];
    const float* fc1_w  = (const float*)d_in[10];
    const float* fc1_b  = (const float*)d_in[11];
    const float* fc2_w  = (const float*)d_in[12];
    const float* fc2_b  = (const float*)d_in[13];

    char* wsb = (char*)d_ws;
    size_t off = 0;
    auto alloc = [&](size_t bytes) -> void* {
        void* p = wsb + off;
        off += (bytes + 255) & ~(size_t)255;
        return p;
    };
    int*   cnt_out = (int*)alloc((size_t)N_NODES * 4);
    int*   cnt_in  = (int*)alloc((size_t)N_NODES * 4);
    int*   row_ptr = (int*)alloc((size_t)(N_NODES + 1) * 4);
    int*   wr_off  = (int*)alloc((size_t)(N_NODES + 1) * 4);
    int*   e_src   = (int*)alloc((size_t)N_EDGES * 4);
    float* inv_out = (float*)alloc((size_t)N_NODES * 4);
    float* inv_in  = (float*)alloc((size_t)N_NODES * 4);
    float* Y       = (float*)alloc((size_t)N_NODES * HID * 4);
    float* X       = (float*)alloc((size_t)N_NODES * HID * 4);
    float* scale   = (float*)alloc(HID * 4);
    float* shift   = (float*)alloc(HID * 4);
    float* H       = (float*)alloc((size_t)N_GRAPHS * HID * 4);
    int*   bsum    = (int*)alloc((size_t)SCAN_B * 4);
    int*   boff    = (int*)alloc((size_t)SCAN_B * 4);

    float* emb_out = (float*)d_out;                // [128,128]
    float* lsm_out = emb_out + N_GRAPHS * HID;     // [128,10]

    hipMemsetAsync(cnt_out, 0, (size_t)N_NODES * 4, stream);
    hipMemsetAsync(cnt_in,  0, (size_t)N_NODES * 4, stream);
    hipMemsetAsync(emb_out, 0, (size_t)N_GRAPHS * HID * 4, stream);  // pool accumulates atomically

    hist_kernel<<<(N_EDGES + 255) / 256, 256, 0, stream>>>(src, dst, cnt_out, cnt_in);
    invsqrt_kernel<<<(N_NODES + 255) / 256, 256, 0, stream>>>(cnt_out, cnt_in, inv_out, inv_in);
    scan_sum_kernel<<<N_SCAN_BLOCKS, SCAN_B, 0, stream>>>(cnt_in, bsum);
    scan_bsum_kernel<<<1, SCAN_B, 0, stream>>>(bsum, boff);
    scan_write_kernel<<<N_SCAN_BLOCKS, SCAN_B, 0, stream>>>(cnt_in, boff, row_ptr, wr_off);
    csr_fill_kernel<<<(N_EDGES + 255) / 256, 256, 0, stream>>>(src, dst, wr_off, e_src);

    // layer 1
    matmul_kernel<<<(N_NODES + 63) / 64, 256, 0, stream>>>(n_feat, inv_out, W1, Y);
    agg_kernel<<<(N_NODES + 3) / 4, 256, 0, stream>>>(Y, e_src, row_ptr, inv_in, b1, X);
    // layer 2
    matmul_kernel<<<(N_NODES + 63) / 64, 256, 0, stream>>>(X, inv_out, W2, Y);
    agg_kernel<<<(N_NODES + 3) / 4, 256, 0, stream>>>(Y, e_src, row_ptr, inv_in, b2, X);

    // pooling -> embedding output (atomic segment-sum; emb zeroed above)
    pool_kernel<<<N_POOL_BLOCKS, 64, 0, stream>>>(X, gid, emb_out);
    // head
    bnstats_kernel<<<1, HID, 0, stream>>>(emb_out, gamma, beta, scale, shift);
    fc1_kernel<<<N_GRAPHS, HID, 0, stream>>>(emb_out, scale, shift, fc1_w, fc1_b, H);
    head_kernel<<<N_GRAPHS, 64, 0, stream>>>(H, fc2_w, fc2_b, lsm_out);
}

// Round 4
// 390.324 us; speedup vs baseline: 1.6481x; 1.1548x over previous
//
#include <hip/hip_runtime.h>
#include <math.h>

#define N_NODES 50000
#define N_EDGES 800000
#define HID 128
#define N_GRAPHS 128
#define OUTC 10
#define BN_EPS 1e-5f

#define SCAN_B 256
#define N_SCAN_BLOCKS ((N_NODES + SCAN_B - 1) / SCAN_B)  // 196

#define POOL_CHUNK 32
#define N_POOL_BLOCKS ((N_NODES + POOL_CHUNK - 1) / POOL_CHUNK)  // 1563

#define HB 80               // histogram blocks per index array
#define HWORDS (N_NODES / 2)  // 25000 packed u32 words (2 x u16 bins)

// ---------------- LDS partial histograms (no global atomics) ----------------
// blocks [0,HB): histogram src; blocks [HB,2*HB): histogram dst.
// Per-block 16-bit counts (<=10000 edges/block) packed 2 bins/u32 in LDS.
__global__ __launch_bounds__(1024) void hist_part_kernel(const int* __restrict__ src,
                                                         const int* __restrict__ dst,
                                                         unsigned int* __restrict__ part) {
    __shared__ unsigned int h[HWORDS];  // 100 KB
    for (int i = threadIdx.x; i < HWORDS; i += 1024) h[i] = 0;
    __syncthreads();
    int half = (blockIdx.x >= HB) ? 1 : 0;
    const int* __restrict__ idx = half ? dst : src;
    int b = blockIdx.x - half * HB;
    for (int e = b * 1024 + threadIdx.x; e < N_EDGES; e += HB * 1024) {
        int v = idx[e];
        atomicAdd(&h[v >> 1], 1u << ((v & 1) << 4));  // LDS atomic, CU-local
    }
    __syncthreads();
    unsigned int* __restrict__ out = part + (size_t)blockIdx.x * HWORDS;
    for (int i = threadIdx.x; i < HWORDS; i += 1024) out[i] = h[i];
}

// Sum partials; emit cnt_in (for scan) + inv_out/inv_in directly.
// Packed-half summation cannot carry: per-bin totals (~16 avg, max << 65536).
__global__ void hist_reduce_kernel(const unsigned int* __restrict__ part,
                                   int* __restrict__ cnt_in,
                                   float* __restrict__ inv_out, float* __restrict__ inv_in) {
    int w = blockIdx.x * blockDim.x + threadIdx.x;
    if (w >= HWORDS) return;
    unsigned int s = 0, d = 0;
    for (int b = 0; b < HB; b++) {
        s += part[(size_t)b * HWORDS + w];
        d += part[(size_t)(b + HB) * HWORDS + w];
    }
    int i0 = w * 2, i1 = i0 + 1;
    int so0 = (int)(s & 0xFFFFu), so1 = (int)(s >> 16);
    int di0 = (int)(d & 0xFFFFu), di1 = (int)(d >> 16);
    cnt_in[i0] = di0;
    cnt_in[i1] = di1;
    inv_out[i0] = rsqrtf(fmaxf((float)so0, 1.0f));
    inv_out[i1] = rsqrtf(fmaxf((float)so1, 1.0f));
    inv_in[i0] = rsqrtf(fmaxf((float)di0, 1.0f));
    inv_in[i1] = rsqrtf(fmaxf((float)di1, 1.0f));
}

// ---------------- 3-phase exclusive scan over in-degrees ----------------
__global__ void scan_sum_kernel(const int* __restrict__ cnt, int* __restrict__ bsum) {
    int i = blockIdx.x * SCAN_B + threadIdx.x;
    int v = (i < N_NODES) ? cnt[i] : 0;
#pragma unroll
    for (int o = 32; o > 0; o >>= 1) v += __shfl_down(v, o);
    __shared__ int ws[4];
    int wave = threadIdx.x >> 6, lane = threadIdx.x & 63;
    if (lane == 0) ws[wave] = v;
    __syncthreads();
    if (threadIdx.x == 0) bsum[blockIdx.x] = ws[0] + ws[1] + ws[2] + ws[3];
}

__global__ void scan_bsum_kernel(const int* __restrict__ bsum, int* __restrict__ boff) {
    __shared__ int part[SCAN_B];
    int t = threadIdx.x;
    int v = (t < N_SCAN_BLOCKS) ? bsum[t] : 0;
    part[t] = v;
    __syncthreads();
    for (int off = 1; off < SCAN_B; off <<= 1) {
        int u = (t >= off) ? part[t - off] : 0;
        __syncthreads();
        part[t] += u;
        __syncthreads();
    }
    boff[t] = part[t] - v;  // exclusive prefix of block sums
}

__global__ void scan_write_kernel(const int* __restrict__ cnt, const int* __restrict__ boff,
                                  int* __restrict__ row_ptr, int* __restrict__ wr_off) {
    __shared__ int part[SCAN_B];
    int t = threadIdx.x;
    int i = blockIdx.x * SCAN_B + t;
    int v = (i < N_NODES) ? cnt[i] : 0;
    part[t] = v;
    __syncthreads();
    for (int off = 1; off < SCAN_B; off <<= 1) {
        int u = (t >= off) ? part[t - off] : 0;
        __syncthreads();
        part[t] += u;
        __syncthreads();
    }
    if (i < N_NODES) {
        int ex = part[t] - v + boff[blockIdx.x];
        row_ptr[i] = ex;
        wr_off[i] = ex;
    }
    if (i == 0) row_ptr[N_NODES] = N_EDGES;
}

// ---------------- CSR fill: edges bucketed by dst, value = src ----------------
__global__ void csr_fill_kernel(const int* __restrict__ src, const int* __restrict__ dst,
                                int* __restrict__ write_off, int* __restrict__ edge_src) {
    int e = blockIdx.x * blockDim.x + threadIdx.x;
    if (e < N_EDGES) {
        int d = dst[e];
        int pos = atomicAdd(&write_off[d], 1);
        edge_src[pos] = src[e];
    }
}

// ---------------- Y[r][:] = (scale[r]*X[r][:]) @ W  (fp32, LDS-tiled) ----------------
__global__ __launch_bounds__(256) void matmul_kernel(const float* __restrict__ X,
                                                     const float* __restrict__ scale,
                                                     const float* __restrict__ W,
                                                     float* __restrict__ Y) {
    __shared__ float xs[64 * HID];   // 32 KB
    __shared__ float wsh[32 * HID];  // 16 KB
    int tid = threadIdx.x;
    int row0 = blockIdx.x * 64;

    for (int j = 0; j < 8; j++) {
        int idx = (j * 256 + tid) * 4;
        int r = row0 + (idx >> 7);
        float4 v = make_float4(0.f, 0.f, 0.f, 0.f);
        if (r < N_NODES) {
            v = *(const float4*)&X[(size_t)r * HID + (idx & 127)];
            float sc = scale[r];
            v.x *= sc; v.y *= sc; v.z *= sc; v.w *= sc;
        }
        *(float4*)&xs[idx] = v;
    }

    int cx = tid & 31;
    int ry = tid >> 5;
    float acc[8][4] = {};

    for (int kt = 0; kt < HID; kt += 32) {
        __syncthreads();
        for (int j = 0; j < 4; j++) {
            int idx = (j * 256 + tid) * 4;
            *(float4*)&wsh[idx] = *(const float4*)&W[kt * HID + idx];
        }
        __syncthreads();
        for (int k = 0; k < 32; k += 4) {
            float4 w0 = *(float4*)&wsh[(k + 0) * HID + cx * 4];
            float4 w1 = *(float4*)&wsh[(k + 1) * HID + cx * 4];
            float4 w2 = *(float4*)&wsh[(k + 2) * HID + cx * 4];
            float4 w3 = *(float4*)&wsh[(k + 3) * HID + cx * 4];
#pragma unroll
            for (int i = 0; i < 8; i++) {
                const float4 xv = *(float4*)&xs[(ry * 8 + i) * HID + kt + k];
                acc[i][0] += xv.x * w0.x + xv.y * w1.x + xv.z * w2.x + xv.w * w3.x;
                acc[i][1] += xv.x * w0.y + xv.y * w1.y + xv.z * w2.y + xv.w * w3.y;
                acc[i][2] += xv.x * w0.z + xv.y * w1.z + xv.z * w2.z + xv.w * w3.z;
                acc[i][3] += xv.x * w0.w + xv.y * w1.w + xv.z * w2.w + xv.w * w3.w;
            }
        }
    }

#pragma unroll
    for (int i = 0; i < 8; i++) {
        int r = row0 + ry * 8 + i;
        if (r < N_NODES)
            *(float4*)&Y[(size_t)r * HID + cx * 4] =
                make_float4(acc[i][0], acc[i][1], acc[i][2], acc[i][3]);
    }
}

// ---------------- CSR gather-accumulate ----------------
__global__ __launch_bounds__(256) void agg_kernel(const float* __restrict__ Y,
                                                  const int* __restrict__ edge_src,
                                                  const int* __restrict__ row_ptr,
                                                  const float* __restrict__ inv_in,
                                                  const float* __restrict__ bias,
                                                  float* __restrict__ Xout) {
    int wave = threadIdx.x >> 6;
    int lane = threadIdx.x & 63;
    int n = blockIdx.x * 4 + wave;
    if (n >= N_NODES) return;
    int beg = row_ptr[n], end = row_ptr[n + 1];
    float ax = 0.f, ay = 0.f;
    for (int base = beg; base < end; base += 64) {
        int cnt = min(64, end - base);
        int idx = (lane < cnt) ? edge_src[base + lane] : 0;
        for (int j = 0; j < cnt; j++) {
            int s = __shfl(idx, j);
            float2 v = *(const float2*)&Y[(size_t)s * HID + lane * 2];
            ax += v.x;
            ay += v.y;
        }
    }
    float si = inv_in[n];
    float2 b = *(const float2*)&bias[lane * 2];
    float2 o = make_float2(fmaxf(ax * si + b.x, 0.f), fmaxf(ay * si + b.y, 0.f));
    *(float2*)&Xout[(size_t)n * HID + lane * 2] = o;
}

// ---------------- SumPooling: chunked segment-sum over sorted gid ----------------
__global__ __launch_bounds__(64) void pool_kernel(const float* __restrict__ X,
                                                  const int* __restrict__ gid,
                                                  float* __restrict__ emb) {
    int lane = threadIdx.x;  // 64, feature pair lane*2, lane*2+1
    int n0 = blockIdx.x * POOL_CHUNK;
    int n1 = min(n0 + POOL_CHUNK, N_NODES);
    if (n0 >= N_NODES) return;
    int g_cur = gid[n0];
    float ax = 0.f, ay = 0.f;
    for (int n = n0; n < n1; n++) {
        int g = gid[n];
        if (g != g_cur) {  // wave-uniform branch
            atomicAdd(&emb[g_cur * HID + lane * 2], ax);
            atomicAdd(&emb[g_cur * HID + lane * 2 + 1], ay);
            ax = 0.f; ay = 0.f;
            g_cur = g;
        }
        float2 v = *(const float2*)&X[(size_t)n * HID + lane * 2];
        ax += v.x;
        ay += v.y;
    }
    atomicAdd(&emb[g_cur * HID + lane * 2], ax);
    atomicAdd(&emb[g_cur * HID + lane * 2 + 1], ay);
}

// ---------------- BatchNorm batch stats -> per-feature scale/shift ----------------
__global__ void bnstats_kernel(const float* __restrict__ emb, const float* __restrict__ gamma,
                               const float* __restrict__ beta, float* __restrict__ scale,
                               float* __restrict__ shift) {
    int f = threadIdx.x;  // 128
    float s = 0.f;
    for (int r = 0; r < N_GRAPHS; r++) s += emb[r * HID + f];
    float mu = s * (1.f / N_GRAPHS);
    float v = 0.f;
    for (int r = 0; r < N_GRAPHS; r++) {
        float d = emb[r * HID + f] - mu;
        v += d * d;
    }
    v *= (1.f / N_GRAPHS);
    float sc = gamma[f] * rsqrtf(v + BN_EPS);
    scale[f] = sc;
    shift[f] = beta[f] - mu * sc;
}

// ---------------- fc1 ----------------
__global__ void fc1_kernel(const float* __restrict__ emb, const float* __restrict__ scale,
                           const float* __restrict__ shift, const float* __restrict__ W,
                           const float* __restrict__ b, float* __restrict__ H) {
    __shared__ float xr[HID];
    int r = blockIdx.x, c = threadIdx.x;  // 128 threads
    xr[c] = emb[r * HID + c] * scale[c] + shift[c];
    __syncthreads();
    float acc = b[c];
    for (int k = 0; k < HID; k++) acc += xr[k] * W[k * HID + c];
    H[r * HID + c] = fmaxf(acc, 0.f);
}

// ---------------- fc2 + log_softmax ----------------
__global__ void head_kernel(const float* __restrict__ H, const float* __restrict__ W,
                            const float* __restrict__ b, float* __restrict__ out) {
    __shared__ float hr[HID];
    __shared__ float logits[OUTC];
    __shared__ float mstat[2];
    int r = blockIdx.x, t = threadIdx.x;  // 64 threads
    hr[t] = H[r * HID + t];
    hr[t + 64] = H[r * HID + t + 64];
    __syncthreads();
    if (t < OUTC) {
        float acc = b[t];
        for (int k = 0; k < HID; k++) acc += hr[k] * W[k * OUTC + t];
        logits[t] = acc;
    }
    __syncthreads();
    if (t == 0) {
        float m = logits[0];
        for (int o = 1; o < OUTC; o++) m = fmaxf(m, logits[o]);
        float sum = 0.f;
        for (int o = 0; o < OUTC; o++) sum += expf(logits[o] - m);
        mstat[0] = m;
        mstat[1] = logf(sum);
    }
    __syncthreads();
    if (t < OUTC) out[r * OUTC + t] = logits[t] - mstat[0] - mstat[1];
}

extern "C" void kernel_launch(void* const* d_in, const int* in_sizes, int n_in,
                              void* d_out, int out_size, void* d_ws, size_t ws_size,
                              hipStream_t stream) {
    const float* n_feat = (const float*)d_in[0];
    const int*   src    = (const int*)d_in[1];
    const int*   dst    = (const int*)d_in[2];
    const int*   gid    = (const int*)d_in[3];
    const float* W1     = (const float*)d_in[4];
    const float* b1     = (const float*)d_in[5];
    const float* W2     = (const float*)d_in[6];
    const float* b2     = (const float*)d_in[7];
    const float* gamma  = (const float*)d_in[8];
    const float* beta   = (const float*)d_in[9];
    const float* fc1_w  = (const float*)d_in[10];
    const float* fc1_b  = (const float*)d_in[11];
    const float* fc2_w  = (const float*)d_in[12];
    const float* fc2_b  = (const float*)d_in[13];

    char* wsb = (char*)d_ws;
    size_t off = 0;
    auto alloc = [&](size_t bytes) -> void* {
        void* p = wsb + off;
        off += (bytes + 255) & ~(size_t)255;
        return p;
    };
    int*   cnt_in  = (int*)alloc((size_t)N_NODES * 4);
    int*   row_ptr = (int*)alloc((size_t)(N_NODES + 1) * 4);
    int*   wr_off  = (int*)alloc((size_t)(N_NODES + 1) * 4);
    int*   e_src   = (int*)alloc((size_t)N_EDGES * 4);
    float* inv_out = (float*)alloc((size_t)N_NODES * 4);
    float* inv_in  = (float*)alloc((size_t)N_NODES * 4);
    float* Y       = (float*)alloc((size_t)N_NODES * HID * 4);
    float* X       = (float*)alloc((size_t)N_NODES * HID * 4);
    float* scale   = (float*)alloc(HID * 4);
    float* shift   = (float*)alloc(HID * 4);
    float* H       = (float*)alloc((size_t)N_GRAPHS * HID * 4);
    int*   bsum    = (int*)alloc((size_t)SCAN_B * 4);
    int*   boff    = (int*)alloc((size_t)SCAN_B * 4);

    // partial histograms (2*HB x HWORDS u32 = 16 MB) alias Y: dead before matmul writes Y
    unsigned int* part = (unsigned int*)Y;

    float* emb_out = (float*)d_out;                // [128,128]
    float* lsm_out = emb_out + N_GRAPHS * HID;     // [128,10]

    hipMemsetAsync(emb_out, 0, (size_t)N_GRAPHS * HID * 4, stream);  // pool accumulates atomically

    hist_part_kernel<<<2 * HB, 1024, 0, stream>>>(src, dst, part);
    hist_reduce_kernel<<<(HWORDS + 255) / 256, 256, 0, stream>>>(part, cnt_in, inv_out, inv_in);
    scan_sum_kernel<<<N_SCAN_BLOCKS, SCAN_B, 0, stream>>>(cnt_in, bsum);
    scan_bsum_kernel<<<1, SCAN_B, 0, stream>>>(bsum, boff);
    scan_write_kernel<<<N_SCAN_BLOCKS, SCAN_B, 0, stream>>>(cnt_in, boff, row_ptr, wr_off);
    csr_fill_kernel<<<(N_EDGES + 255) / 256, 256, 0, stream>>>(src, dst, wr_off, e_src);

    // layer 1
    matmul_kernel<<<(N_NODES + 63) / 64, 256, 0, stream>>>(n_feat, inv_out, W1, Y);
    agg_kernel<<<(N_NODES + 3) / 4, 256, 0, stream>>>(Y, e_src, row_ptr, inv_in, b1, X);
    // layer 2
    matmul_kernel<<<(N_NODES + 63) / 64, 256, 0, stream>>>(X, inv_out, W2, Y);
    agg_kernel<<<(N_NODES + 3) / 4, 256, 0, stream>>>(Y, e_src, row_ptr, inv_in, b2, X);

    // pooling -> embedding output (atomic segment-sum; emb zeroed above)
    pool_kernel<<<N_POOL_BLOCKS, 64, 0, stream>>>(X, gid, emb_out);
    // head
    bnstats_kernel<<<1, HID, 0, stream>>>(emb_out, gamma, beta, scale, shift);
    fc1_kernel<<<N_GRAPHS, HID, 0, stream>>>(emb_out, scale, shift, fc1_w, fc1_b, H);
    head_kernel<<<N_GRAPHS, 64, 0, stream>>>(H, fc2_w, fc2_b, lsm_out);
}

// Round 5
// 372.604 us; speedup vs baseline: 1.7265x; 1.0476x over previous
//
#include <hip/hip_runtime.h>
#include <hip/hip_bf16.h>
#include <math.h>

#define N_NODES 50000
#define N_EDGES 800000
#define HID 128
#define N_GRAPHS 128
#define OUTC 10
#define BN_EPS 1e-5f

#define SCAN_B 256
#define N_SCAN_BLOCKS ((N_NODES + SCAN_B - 1) / SCAN_B)  // 196

#define POOL_CHUNK 32
#define N_POOL_BLOCKS ((N_NODES + POOL_CHUNK - 1) / POOL_CHUNK)  // 1563

#define HB 80                 // histogram blocks per index array
#define HWORDS (N_NODES / 2)  // 25000 packed u32 words (2 x u16 bins)

// ---------------- LDS partial histograms (no global atomics) ----------------
__global__ __launch_bounds__(1024) void hist_part_kernel(const int* __restrict__ src,
                                                         const int* __restrict__ dst,
                                                         unsigned int* __restrict__ part) {
    __shared__ unsigned int h[HWORDS];  // 100 KB
    for (int i = threadIdx.x; i < HWORDS; i += 1024) h[i] = 0;
    __syncthreads();
    int half = (blockIdx.x >= HB) ? 1 : 0;
    const int* __restrict__ idx = half ? dst : src;
    int b = blockIdx.x - half * HB;
    for (int e = b * 1024 + threadIdx.x; e < N_EDGES; e += HB * 1024) {
        int v = idx[e];
        atomicAdd(&h[v >> 1], 1u << ((v & 1) << 4));  // LDS atomic, CU-local
    }
    __syncthreads();
    unsigned int* __restrict__ out = part + (size_t)blockIdx.x * HWORDS;
    for (int i = threadIdx.x; i < HWORDS; i += 1024) out[i] = h[i];
}

__global__ void hist_reduce_kernel(const unsigned int* __restrict__ part,
                                   int* __restrict__ cnt_in,
                                   float* __restrict__ inv_out, float* __restrict__ inv_in) {
    int w = blockIdx.x * blockDim.x + threadIdx.x;
    if (w >= HWORDS) return;
    unsigned int s = 0, d = 0;
    for (int b = 0; b < HB; b++) {
        s += part[(size_t)b * HWORDS + w];
        d += part[(size_t)(b + HB) * HWORDS + w];
    }
    int i0 = w * 2, i1 = i0 + 1;
    int so0 = (int)(s & 0xFFFFu), so1 = (int)(s >> 16);
    int di0 = (int)(d & 0xFFFFu), di1 = (int)(d >> 16);
    cnt_in[i0] = di0;
    cnt_in[i1] = di1;
    inv_out[i0] = rsqrtf(fmaxf((float)so0, 1.0f));
    inv_out[i1] = rsqrtf(fmaxf((float)so1, 1.0f));
    inv_in[i0] = rsqrtf(fmaxf((float)di0, 1.0f));
    inv_in[i1] = rsqrtf(fmaxf((float)di1, 1.0f));
}

// ---------------- 3-phase exclusive scan over in-degrees ----------------
__global__ void scan_sum_kernel(const int* __restrict__ cnt, int* __restrict__ bsum) {
    int i = blockIdx.x * SCAN_B + threadIdx.x;
    int v = (i < N_NODES) ? cnt[i] : 0;
#pragma unroll
    for (int o = 32; o > 0; o >>= 1) v += __shfl_down(v, o);
    __shared__ int ws[4];
    int wave = threadIdx.x >> 6, lane = threadIdx.x & 63;
    if (lane == 0) ws[wave] = v;
    __syncthreads();
    if (threadIdx.x == 0) bsum[blockIdx.x] = ws[0] + ws[1] + ws[2] + ws[3];
}

__global__ void scan_bsum_kernel(const int* __restrict__ bsum, int* __restrict__ boff) {
    __shared__ int part[SCAN_B];
    int t = threadIdx.x;
    int v = (t < N_SCAN_BLOCKS) ? bsum[t] : 0;
    part[t] = v;
    __syncthreads();
    for (int off = 1; off < SCAN_B; off <<= 1) {
        int u = (t >= off) ? part[t - off] : 0;
        __syncthreads();
        part[t] += u;
        __syncthreads();
    }
    boff[t] = part[t] - v;
}

__global__ void scan_write_kernel(const int* __restrict__ cnt, const int* __restrict__ boff,
                                  int* __restrict__ row_ptr, int* __restrict__ wr_off) {
    __shared__ int part[SCAN_B];
    int t = threadIdx.x;
    int i = blockIdx.x * SCAN_B + t;
    int v = (i < N_NODES) ? cnt[i] : 0;
    part[t] = v;
    __syncthreads();
    for (int off = 1; off < SCAN_B; off <<= 1) {
        int u = (t >= off) ? part[t - off] : 0;
        __syncthreads();
        part[t] += u;
        __syncthreads();
    }
    if (i < N_NODES) {
        int ex = part[t] - v + boff[blockIdx.x];
        row_ptr[i] = ex;
        wr_off[i] = ex;
    }
    if (i == 0) row_ptr[N_NODES] = N_EDGES;
}

// ---------------- CSR fill ----------------
__global__ void csr_fill_kernel(const int* __restrict__ src, const int* __restrict__ dst,
                                int* __restrict__ write_off, int* __restrict__ edge_src) {
    int e = blockIdx.x * blockDim.x + threadIdx.x;
    if (e < N_EDGES) {
        int d = dst[e];
        int pos = atomicAdd(&write_off[d], 1);
        edge_src[pos] = src[e];
    }
}

// ---------------- Y[r][:] = bf16( (scale[r]*X[r][:]) @ W )  (fp32 compute) ----------------
__global__ __launch_bounds__(256) void matmul_kernel(const float* __restrict__ X,
                                                     const float* __restrict__ scale,
                                                     const float* __restrict__ W,
                                                     __hip_bfloat16* __restrict__ Y) {
    __shared__ float xs[64 * HID];   // 32 KB
    __shared__ float wsh[32 * HID];  // 16 KB
    int tid = threadIdx.x;
    int row0 = blockIdx.x * 64;

    for (int j = 0; j < 8; j++) {
        int idx = (j * 256 + tid) * 4;
        int r = row0 + (idx >> 7);
        float4 v = make_float4(0.f, 0.f, 0.f, 0.f);
        if (r < N_NODES) {
            v = *(const float4*)&X[(size_t)r * HID + (idx & 127)];
            float sc = scale[r];
            v.x *= sc; v.y *= sc; v.z *= sc; v.w *= sc;
        }
        *(float4*)&xs[idx] = v;
    }

    int cx = tid & 31;
    int ry = tid >> 5;
    float acc[8][4] = {};

    for (int kt = 0; kt < HID; kt += 32) {
        __syncthreads();
        for (int j = 0; j < 4; j++) {
            int idx = (j * 256 + tid) * 4;
            *(float4*)&wsh[idx] = *(const float4*)&W[kt * HID + idx];
        }
        __syncthreads();
        for (int k = 0; k < 32; k += 4) {
            float4 w0 = *(float4*)&wsh[(k + 0) * HID + cx * 4];
            float4 w1 = *(float4*)&wsh[(k + 1) * HID + cx * 4];
            float4 w2 = *(float4*)&wsh[(k + 2) * HID + cx * 4];
            float4 w3 = *(float4*)&wsh[(k + 3) * HID + cx * 4];
#pragma unroll
            for (int i = 0; i < 8; i++) {
                const float4 xv = *(float4*)&xs[(ry * 8 + i) * HID + kt + k];
                acc[i][0] += xv.x * w0.x + xv.y * w1.x + xv.z * w2.x + xv.w * w3.x;
                acc[i][1] += xv.x * w0.y + xv.y * w1.y + xv.z * w2.y + xv.w * w3.y;
                acc[i][2] += xv.x * w0.z + xv.y * w1.z + xv.z * w2.z + xv.w * w3.z;
                acc[i][3] += xv.x * w0.w + xv.y * w1.w + xv.z * w2.w + xv.w * w3.w;
            }
        }
    }

#pragma unroll
    for (int i = 0; i < 8; i++) {
        int r = row0 + ry * 8 + i;
        if (r < N_NODES) {
            ushort4 o;
            o.x = __hip_bfloat16_raw(__float2bfloat16(acc[i][0])).x;
            o.y = __hip_bfloat16_raw(__float2bfloat16(acc[i][1])).x;
            o.z = __hip_bfloat16_raw(__float2bfloat16(acc[i][2])).x;
            o.w = __hip_bfloat16_raw(__float2bfloat16(acc[i][3])).x;
            *(ushort4*)&Y[(size_t)r * HID + cx * 4] = o;
        }
    }
}

// ---------------- CSR gather-accumulate over bf16 Y (fp32 accumulate) ----------------
// one wave per node; lane covers feats {2*lane, 2*lane+1}; 4 B load per edge-row.
__global__ __launch_bounds__(256) void agg_kernel(const __hip_bfloat16* __restrict__ Y,
                                                  const int* __restrict__ edge_src,
                                                  const int* __restrict__ row_ptr,
                                                  const float* __restrict__ inv_in,
                                                  const float* __restrict__ bias,
                                                  float* __restrict__ Xout) {
    const unsigned int* __restrict__ Yw = (const unsigned int*)Y;  // 2 bf16 per word
    int wave = threadIdx.x >> 6;
    int lane = threadIdx.x & 63;
    int n = blockIdx.x * 4 + wave;
    if (n >= N_NODES) return;
    int beg = row_ptr[n], end = row_ptr[n + 1];
    float ax = 0.f, ay = 0.f;
    for (int base = beg; base < end; base += 64) {
        int cnt = min(64, end - base);
        int idx = (lane < cnt) ? edge_src[base + lane] : 0;
        for (int j = 0; j < cnt; j++) {
            int s = __shfl(idx, j);
            unsigned int u = Yw[(size_t)s * (HID / 2) + lane];
            float lo = __uint_as_float(u << 16);
            float hi = __uint_as_float(u & 0xFFFF0000u);
            ax += lo;
            ay += hi;
        }
    }
    float si = inv_in[n];
    float2 b = *(const float2*)&bias[lane * 2];
    float2 o = make_float2(fmaxf(ax * si + b.x, 0.f), fmaxf(ay * si + b.y, 0.f));
    *(float2*)&Xout[(size_t)n * HID + lane * 2] = o;
}

// ---------------- SumPooling: chunked segment-sum over sorted gid ----------------
__global__ __launch_bounds__(64) void pool_kernel(const float* __restrict__ X,
                                                  const int* __restrict__ gid,
                                                  float* __restrict__ emb) {
    int lane = threadIdx.x;
    int n0 = blockIdx.x * POOL_CHUNK;
    int n1 = min(n0 + POOL_CHUNK, N_NODES);
    if (n0 >= N_NODES) return;
    int g_cur = gid[n0];
    float ax = 0.f, ay = 0.f;
    for (int n = n0; n < n1; n++) {
        int g = gid[n];
        if (g != g_cur) {
            atomicAdd(&emb[g_cur * HID + lane * 2], ax);
            atomicAdd(&emb[g_cur * HID + lane * 2 + 1], ay);
            ax = 0.f; ay = 0.f;
            g_cur = g;
        }
        float2 v = *(const float2*)&X[(size_t)n * HID + lane * 2];
        ax += v.x;
        ay += v.y;
    }
    atomicAdd(&emb[g_cur * HID + lane * 2], ax);
    atomicAdd(&emb[g_cur * HID + lane * 2 + 1], ay);
}

// ---------------- BatchNorm batch stats ----------------
__global__ void bnstats_kernel(const float* __restrict__ emb, const float* __restrict__ gamma,
                               const float* __restrict__ beta, float* __restrict__ scale,
                               float* __restrict__ shift) {
    int f = threadIdx.x;  // 128
    float s = 0.f;
    for (int r = 0; r < N_GRAPHS; r++) s += emb[r * HID + f];
    float mu = s * (1.f / N_GRAPHS);
    float v = 0.f;
    for (int r = 0; r < N_GRAPHS; r++) {
        float d = emb[r * HID + f] - mu;
        v += d * d;
    }
    v *= (1.f / N_GRAPHS);
    float sc = gamma[f] * rsqrtf(v + BN_EPS);
    scale[f] = sc;
    shift[f] = beta[f] - mu * sc;
}

// ---------------- fc1 ----------------
__global__ void fc1_kernel(const float* __restrict__ emb, const float* __restrict__ scale,
                           const float* __restrict__ shift, const float* __restrict__ W,
                           const float* __restrict__ b, float* __restrict__ H) {
    __shared__ float xr[HID];
    int r = blockIdx.x, c = threadIdx.x;  // 128 threads
    xr[c] = emb[r * HID + c] * scale[c] + shift[c];
    __syncthreads();
    float acc = b[c];
    for (int k = 0; k < HID; k++) acc += xr[k] * W[k * HID + c];
    H[r * HID + c] = fmaxf(acc, 0.f);
}

// ---------------- fc2 + log_softmax ----------------
__global__ void head_kernel(const float* __restrict__ H, const float* __restrict__ W,
                            const float* __restrict__ b, float* __restrict__ out) {
    __shared__ float hr[HID];
    __shared__ float logits[OUTC];
    __shared__ float mstat[2];
    int r = blockIdx.x, t = threadIdx.x;  // 64 threads
    hr[t] = H[r * HID + t];
    hr[t + 64] = H[r * HID + t + 64];
    __syncthreads();
    if (t < OUTC) {
        float acc = b[t];
        for (int k = 0; k < HID; k++) acc += hr[k] * W[k * OUTC + t];
        logits[t] = acc;
    }
    __syncthreads();
    if (t == 0) {
        float m = logits[0];
        for (int o = 1; o < OUTC; o++) m = fmaxf(m, logits[o]);
        float sum = 0.f;
        for (int o = 0; o < OUTC; o++) sum += expf(logits[o] - m);
        mstat[0] = m;
        mstat[1] = logf(sum);
    }
    __syncthreads();
    if (t < OUTC) out[r * OUTC + t] = logits[t] - mstat[0] - mstat[1];
}

extern "C" void kernel_launch(void* const* d_in, const int* in_sizes, int n_in,
                              void* d_out, int out_size, void* d_ws, size_t ws_size,
                              hipStream_t stream) {
    const float* n_feat = (const float*)d_in[0];
    const int*   src    = (const int*)d_in[1];
    const int*   dst    = (const int*)d_in[2];
    const int*   gid    = (const int*)d_in[3];
    const float* W1     = (const float*)d_in[4];
    const float* b1     = (const float*)d_in[5];
    const float* W2     = (const float*)d_in[6];
    const float* b2     = (const float*)d_in[7];
    const float* gamma  = (const float*)d_in[8];
    const float* beta   = (const float*)d_in[9];
    const float* fc1_w  = (const float*)d_in[10];
    const float* fc1_b  = (const float*)d_in[11];
    const float* fc2_w  = (const float*)d_in[12];
    const float* fc2_b  = (const float*)d_in[13];

    char* wsb = (char*)d_ws;
    size_t off = 0;
    auto alloc = [&](size_t bytes) -> void* {
        void* p = wsb + off;
        off += (bytes + 255) & ~(size_t)255;
        return p;
    };
    int*   cnt_in  = (int*)alloc((size_t)N_NODES * 4);
    int*   row_ptr = (int*)alloc((size_t)(N_NODES + 1) * 4);
    int*   wr_off  = (int*)alloc((size_t)(N_NODES + 1) * 4);
    int*   e_src   = (int*)alloc((size_t)N_EDGES * 4);
    float* inv_out = (float*)alloc((size_t)N_NODES * 4);
    float* inv_in  = (float*)alloc((size_t)N_NODES * 4);
    // ybuf doubles as: partial histograms (2*HB*HWORDS u32 = 16 MB), then bf16 Y (12.8 MB)
    void*  ybuf    = alloc((size_t)2 * HB * HWORDS * 4);
    float* X       = (float*)alloc((size_t)N_NODES * HID * 4);
    float* scale   = (float*)alloc(HID * 4);
    float* shift   = (float*)alloc(HID * 4);
    float* H       = (float*)alloc((size_t)N_GRAPHS * HID * 4);
    int*   bsum    = (int*)alloc((size_t)SCAN_B * 4);
    int*   boff    = (int*)alloc((size_t)SCAN_B * 4);

    unsigned int*   part = (unsigned int*)ybuf;
    __hip_bfloat16* Y    = (__hip_bfloat16*)ybuf;

    float* emb_out = (float*)d_out;                // [128,128]
    float* lsm_out = emb_out + N_GRAPHS * HID;     // [128,10]

    hipMemsetAsync(emb_out, 0, (size_t)N_GRAPHS * HID * 4, stream);

    hist_part_kernel<<<2 * HB, 1024, 0, stream>>>(src, dst, part);
    hist_reduce_kernel<<<(HWORDS + 255) / 256, 256, 0, stream>>>(part, cnt_in, inv_out, inv_in);
    scan_sum_kernel<<<N_SCAN_BLOCKS, SCAN_B, 0, stream>>>(cnt_in, bsum);
    scan_bsum_kernel<<<1, SCAN_B, 0, stream>>>(bsum, boff);
    scan_write_kernel<<<N_SCAN_BLOCKS, SCAN_B, 0, stream>>>(cnt_in, boff, row_ptr, wr_off);
    csr_fill_kernel<<<(N_EDGES + 255) / 256, 256, 0, stream>>>(src, dst, wr_off, e_src);

    // layer 1
    matmul_kernel<<<(N_NODES + 63) / 64, 256, 0, stream>>>(n_feat, inv_out, W1, Y);
    agg_kernel<<<(N_NODES + 3) / 4, 256, 0, stream>>>(Y, e_src, row_ptr, inv_in, b1, X);
    // layer 2
    matmul_kernel<<<(N_NODES + 63) / 64, 256, 0, stream>>>(X, inv_out, W2, Y);
    agg_kernel<<<(N_NODES + 3) / 4, 256, 0, stream>>>(Y, e_src, row_ptr, inv_in, b2, X);

    // pooling -> embedding output
    pool_kernel<<<N_POOL_BLOCKS, 64, 0, stream>>>(X, gid, emb_out);
    // head
    bnstats_kernel<<<1, HID, 0, stream>>>(emb_out, gamma, beta, scale, shift);
    fc1_kernel<<<N_GRAPHS, HID, 0, stream>>>(emb_out, scale, shift, fc1_w, fc1_b, H);
    head_kernel<<<N_GRAPHS, 64, 0, stream>>>(H, fc2_w, fc2_b, lsm_out);
}

// Round 6
// 320.437 us; speedup vs baseline: 2.0076x; 1.1628x over previous
//
#include <hip/hip_runtime.h>
#include <hip/hip_bf16.h>
#include <math.h>

#define N_NODES 50000
#define N_EDGES 800000
#define HID 128
#define N_GRAPHS 128
#define OUTC 10
#define BN_EPS 1e-5f

#define SCAN_B 256
#define N_SCAN_BLOCKS ((N_NODES + SCAN_B - 1) / SCAN_B)  // 196

#define POOL_CHUNK 32
#define N_POOL_BLOCKS ((N_NODES + POOL_CHUNK - 1) / POOL_CHUNK)  // 1563

#define HB 80                 // histogram blocks per index array
#define HWORDS (N_NODES / 2)  // 25000 packed u32 words (2 x u16 bins)

#define EPAD 8                // CSR row padding (edges), multiple of 8 for guard-free inner loop
#define E_SRC_CAP (N_EDGES + N_NODES * EPAD)  // worst-case padded edge slots

// ---------------- LDS partial histograms (no global atomics) ----------------
__global__ __launch_bounds__(1024) void hist_part_kernel(const int* __restrict__ src,
                                                         const int* __restrict__ dst,
                                                         unsigned int* __restrict__ part) {
    __shared__ unsigned int h[HWORDS];  // 100 KB
    for (int i = threadIdx.x; i < HWORDS; i += 1024) h[i] = 0;
    __syncthreads();
    int half = (blockIdx.x >= HB) ? 1 : 0;
    const int* __restrict__ idx = half ? dst : src;
    int b = blockIdx.x - half * HB;
    for (int e = b * 1024 + threadIdx.x; e < N_EDGES; e += HB * 1024) {
        int v = idx[e];
        atomicAdd(&h[v >> 1], 1u << ((v & 1) << 4));  // LDS atomic, CU-local
    }
    __syncthreads();
    unsigned int* __restrict__ out = part + (size_t)blockIdx.x * HWORDS;
    for (int i = threadIdx.x; i < HWORDS; i += 1024) out[i] = h[i];
}

__global__ void hist_reduce_kernel(const unsigned int* __restrict__ part,
                                   int* __restrict__ cnt_in,
                                   float* __restrict__ inv_out, float* __restrict__ inv_in) {
    int w = blockIdx.x * blockDim.x + threadIdx.x;
    if (w >= HWORDS) return;
    unsigned int s = 0, d = 0;
    for (int b = 0; b < HB; b++) {
        s += part[(size_t)b * HWORDS + w];
        d += part[(size_t)(b + HB) * HWORDS + w];
    }
    int i0 = w * 2, i1 = i0 + 1;
    int so0 = (int)(s & 0xFFFFu), so1 = (int)(s >> 16);
    int di0 = (int)(d & 0xFFFFu), di1 = (int)(d >> 16);
    cnt_in[i0] = di0;
    cnt_in[i1] = di1;
    inv_out[i0] = rsqrtf(fmaxf((float)so0, 1.0f));
    inv_out[i1] = rsqrtf(fmaxf((float)so1, 1.0f));
    inv_in[i0] = rsqrtf(fmaxf((float)di0, 1.0f));
    inv_in[i1] = rsqrtf(fmaxf((float)di1, 1.0f));
}

// ---------------- 3-phase exclusive scan over PADDED in-degrees ----------------
__global__ void scan_sum_kernel(const int* __restrict__ cnt, int* __restrict__ bsum) {
    int i = blockIdx.x * SCAN_B + threadIdx.x;
    int v = (i < N_NODES) ? ((cnt[i] + EPAD - 1) & ~(EPAD - 1)) : 0;
#pragma unroll
    for (int o = 32; o > 0; o >>= 1) v += __shfl_down(v, o);
    __shared__ int ws[4];
    int wave = threadIdx.x >> 6, lane = threadIdx.x & 63;
    if (lane == 0) ws[wave] = v;
    __syncthreads();
    if (threadIdx.x == 0) bsum[blockIdx.x] = ws[0] + ws[1] + ws[2] + ws[3];
}

__global__ void scan_bsum_kernel(const int* __restrict__ bsum, int* __restrict__ boff) {
    __shared__ int part[SCAN_B];
    int t = threadIdx.x;
    int v = (t < N_SCAN_BLOCKS) ? bsum[t] : 0;
    part[t] = v;
    __syncthreads();
    for (int off = 1; off < SCAN_B; off <<= 1) {
        int u = (t >= off) ? part[t - off] : 0;
        __syncthreads();
        part[t] += u;
        __syncthreads();
    }
    boff[t] = part[t] - v;
}

__global__ void scan_write_kernel(const int* __restrict__ cnt, const int* __restrict__ boff,
                                  int* __restrict__ row_ptr, int* __restrict__ wr_off) {
    __shared__ int part[SCAN_B];
    int t = threadIdx.x;
    int i = blockIdx.x * SCAN_B + t;
    int v = (i < N_NODES) ? ((cnt[i] + EPAD - 1) & ~(EPAD - 1)) : 0;
    part[t] = v;
    __syncthreads();
    for (int off = 1; off < SCAN_B; off <<= 1) {
        int u = (t >= off) ? part[t - off] : 0;
        __syncthreads();
        part[t] += u;
        __syncthreads();
    }
    if (i < N_NODES) {
        int ex = part[t] - v + boff[blockIdx.x];
        row_ptr[i] = ex;
        wr_off[i] = ex;
        if (i == N_NODES - 1) row_ptr[N_NODES] = ex + v;  // padded total
    }
}

// ---------------- CSR fill ----------------
__global__ void csr_fill_kernel(const int* __restrict__ src, const int* __restrict__ dst,
                                int* __restrict__ write_off, int* __restrict__ edge_src) {
    int e = blockIdx.x * blockDim.x + threadIdx.x;
    if (e < N_EDGES) {
        int d = dst[e];
        int pos = atomicAdd(&write_off[d], 1);
        edge_src[pos] = src[e];
    }
}

// fill padded slots with the dummy zero-row index N_NODES
__global__ void fill_pad_kernel(const int* __restrict__ row_ptr, const int* __restrict__ cnt,
                                int* __restrict__ edge_src) {
    int n = blockIdx.x * blockDim.x + threadIdx.x;
    if (n < N_NODES) {
        int p = row_ptr[n] + cnt[n];
        int e = row_ptr[n + 1];
        for (; p < e; p++) edge_src[p] = N_NODES;
    }
}

// ---------------- Y[r][:] = bf16( (scale[r]*X[r][:]) @ W )  (fp32 compute) ----------------
// Also emits the all-zero dummy row r == N_NODES (X-tile guard zero-fills it).
__global__ __launch_bounds__(256) void matmul_kernel(const float* __restrict__ X,
                                                     const float* __restrict__ scale,
                                                     const float* __restrict__ W,
                                                     __hip_bfloat16* __restrict__ Y) {
    __shared__ float xs[64 * HID];   // 32 KB
    __shared__ float wsh[32 * HID];  // 16 KB
    int tid = threadIdx.x;
    int row0 = blockIdx.x * 64;

    for (int j = 0; j < 8; j++) {
        int idx = (j * 256 + tid) * 4;
        int r = row0 + (idx >> 7);
        float4 v = make_float4(0.f, 0.f, 0.f, 0.f);
        if (r < N_NODES) {
            v = *(const float4*)&X[(size_t)r * HID + (idx & 127)];
            float sc = scale[r];
            v.x *= sc; v.y *= sc; v.z *= sc; v.w *= sc;
        }
        *(float4*)&xs[idx] = v;
    }

    int cx = tid & 31;
    int ry = tid >> 5;
    float acc[8][4] = {};

    for (int kt = 0; kt < HID; kt += 32) {
        __syncthreads();
        for (int j = 0; j < 4; j++) {
            int idx = (j * 256 + tid) * 4;
            *(float4*)&wsh[idx] = *(const float4*)&W[kt * HID + idx];
        }
        __syncthreads();
        for (int k = 0; k < 32; k += 4) {
            float4 w0 = *(float4*)&wsh[(k + 0) * HID + cx * 4];
            float4 w1 = *(float4*)&wsh[(k + 1) * HID + cx * 4];
            float4 w2 = *(float4*)&wsh[(k + 2) * HID + cx * 4];
            float4 w3 = *(float4*)&wsh[(k + 3) * HID + cx * 4];
#pragma unroll
            for (int i = 0; i < 8; i++) {
                const float4 xv = *(float4*)&xs[(ry * 8 + i) * HID + kt + k];
                acc[i][0] += xv.x * w0.x + xv.y * w1.x + xv.z * w2.x + xv.w * w3.x;
                acc[i][1] += xv.x * w0.y + xv.y * w1.y + xv.z * w2.y + xv.w * w3.y;
                acc[i][2] += xv.x * w0.z + xv.y * w1.z + xv.z * w2.z + xv.w * w3.z;
                acc[i][3] += xv.x * w0.w + xv.y * w1.w + xv.z * w2.w + xv.w * w3.w;
            }
        }
    }

#pragma unroll
    for (int i = 0; i < 8; i++) {
        int r = row0 + ry * 8 + i;
        if (r < N_NODES + 1) {  // include dummy zero row
            ushort4 o;
            o.x = __hip_bfloat16_raw(__float2bfloat16(acc[i][0])).x;
            o.y = __hip_bfloat16_raw(__float2bfloat16(acc[i][1])).x;
            o.z = __hip_bfloat16_raw(__float2bfloat16(acc[i][2])).x;
            o.w = __hip_bfloat16_raw(__float2bfloat16(acc[i][3])).x;
            *(ushort4*)&Y[(size_t)r * HID + cx * 4] = o;
        }
    }
}

// ---------------- CSR gather-accumulate over bf16 Y (fp32 accumulate) ----------------
// one wave per node; 4 edges/iteration: lane = esub(0..3) x f16(0..15); dwordx4 loads.
// Rows are padded to a multiple of 8 edges (dummy -> zero row N_NODES): guard-free inner loop.
__global__ __launch_bounds__(256) void agg_kernel(const __hip_bfloat16* __restrict__ Y,
                                                  const int* __restrict__ edge_src,
                                                  const int* __restrict__ row_ptr,
                                                  const float* __restrict__ inv_in,
                                                  const float* __restrict__ bias,
                                                  float* __restrict__ Xout) {
    const uint4* __restrict__ Yq = (const uint4*)Y;  // 8 bf16 per uint4
    int wave = threadIdx.x >> 6;
    int lane = threadIdx.x & 63;
    int n = blockIdx.x * 4 + wave;
    if (n >= N_NODES) return;
    int beg = row_ptr[n], end = row_ptr[n + 1];  // length multiple of 8
    int esub = lane >> 4;   // which of 4 concurrent edges
    int f16  = lane & 15;   // feature quad: feats f16*8 .. f16*8+7
    float acc[8] = {};
    for (int base = beg; base < end; base += 64) {
        int m = min(64, end - base);  // multiple of 8
        int idx = (lane < m) ? edge_src[base + lane] : N_NODES;
        for (int j = 0; j < m; j += 8) {
            int s0 = __shfl(idx, j + esub);
            int s1 = __shfl(idx, j + 4 + esub);
            uint4 u0 = Yq[s0 * (HID / 8) + f16];
            uint4 u1 = Yq[s1 * (HID / 8) + f16];
            acc[0] += __uint_as_float(u0.x << 16); acc[1] += __uint_as_float(u0.x & 0xFFFF0000u);
            acc[2] += __uint_as_float(u0.y << 16); acc[3] += __uint_as_float(u0.y & 0xFFFF0000u);
            acc[4] += __uint_as_float(u0.z << 16); acc[5] += __uint_as_float(u0.z & 0xFFFF0000u);
            acc[6] += __uint_as_float(u0.w << 16); acc[7] += __uint_as_float(u0.w & 0xFFFF0000u);
            acc[0] += __uint_as_float(u1.x << 16); acc[1] += __uint_as_float(u1.x & 0xFFFF0000u);
            acc[2] += __uint_as_float(u1.y << 16); acc[3] += __uint_as_float(u1.y & 0xFFFF0000u);
            acc[4] += __uint_as_float(u1.z << 16); acc[5] += __uint_as_float(u1.z & 0xFFFF0000u);
            acc[6] += __uint_as_float(u1.w << 16); acc[7] += __uint_as_float(u1.w & 0xFFFF0000u);
        }
    }
    // combine the 4 esub groups: lanes differing in bits 4,5 hold same features
#pragma unroll
    for (int i = 0; i < 8; i++) {
        acc[i] += __shfl_xor(acc[i], 16);
        acc[i] += __shfl_xor(acc[i], 32);
    }
    if (lane < 16) {
        float si = inv_in[n];
        int f0 = f16 * 8;
        float4 b0 = *(const float4*)&bias[f0];
        float4 b1 = *(const float4*)&bias[f0 + 4];
        float4 o0, o1;
        o0.x = fmaxf(acc[0] * si + b0.x, 0.f);
        o0.y = fmaxf(acc[1] * si + b0.y, 0.f);
        o0.z = fmaxf(acc[2] * si + b0.z, 0.f);
        o0.w = fmaxf(acc[3] * si + b0.w, 0.f);
        o1.x = fmaxf(acc[4] * si + b1.x, 0.f);
        o1.y = fmaxf(acc[5] * si + b1.y, 0.f);
        o1.z = fmaxf(acc[6] * si + b1.z, 0.f);
        o1.w = fmaxf(acc[7] * si + b1.w, 0.f);
        *(float4*)&Xout[(size_t)n * HID + f0] = o0;
        *(float4*)&Xout[(size_t)n * HID + f0 + 4] = o1;
    }
}

// ---------------- SumPooling: chunked segment-sum over sorted gid ----------------
__global__ __launch_bounds__(64) void pool_kernel(const float* __restrict__ X,
                                                  const int* __restrict__ gid,
                                                  float* __restrict__ emb) {
    int lane = threadIdx.x;
    int n0 = blockIdx.x * POOL_CHUNK;
    int n1 = min(n0 + POOL_CHUNK, N_NODES);
    if (n0 >= N_NODES) return;
    int g_cur = gid[n0];
    float ax = 0.f, ay = 0.f;
    for (int n = n0; n < n1; n++) {
        int g = gid[n];
        if (g != g_cur) {
            atomicAdd(&emb[g_cur * HID + lane * 2], ax);
            atomicAdd(&emb[g_cur * HID + lane * 2 + 1], ay);
            ax = 0.f; ay = 0.f;
            g_cur = g;
        }
        float2 v = *(const float2*)&X[(size_t)n * HID + lane * 2];
        ax += v.x;
        ay += v.y;
    }
    atomicAdd(&emb[g_cur * HID + lane * 2], ax);
    atomicAdd(&emb[g_cur * HID + lane * 2 + 1], ay);
}

// ---------------- BatchNorm batch stats ----------------
__global__ void bnstats_kernel(const float* __restrict__ emb, const float* __restrict__ gamma,
                               const float* __restrict__ beta, float* __restrict__ scale,
                               float* __restrict__ shift) {
    int f = threadIdx.x;  // 128
    float s = 0.f;
    for (int r = 0; r < N_GRAPHS; r++) s += emb[r * HID + f];
    float mu = s * (1.f / N_GRAPHS);
    float v = 0.f;
    for (int r = 0; r < N_GRAPHS; r++) {
        float d = emb[r * HID + f] - mu;
        v += d * d;
    }
    v *= (1.f / N_GRAPHS);
    float sc = gamma[f] * rsqrtf(v + BN_EPS);
    scale[f] = sc;
    shift[f] = beta[f] - mu * sc;
}

// ---------------- fc1 ----------------
__global__ void fc1_kernel(const float* __restrict__ emb, const float* __restrict__ scale,
                           const float* __restrict__ shift, const float* __restrict__ W,
                           const float* __restrict__ b, float* __restrict__ H) {
    __shared__ float xr[HID];
    int r = blockIdx.x, c = threadIdx.x;  // 128 threads
    xr[c] = emb[r * HID + c] * scale[c] + shift[c];
    __syncthreads();
    float acc = b[c];
    for (int k = 0; k < HID; k++) acc += xr[k] * W[k * HID + c];
    H[r * HID + c] = fmaxf(acc, 0.f);
}

// ---------------- fc2 + log_softmax ----------------
__global__ void head_kernel(const float* __restrict__ H, const float* __restrict__ W,
                            const float* __restrict__ b, float* __restrict__ out) {
    __shared__ float hr[HID];
    __shared__ float logits[OUTC];
    __shared__ float mstat[2];
    int r = blockIdx.x, t = threadIdx.x;  // 64 threads
    hr[t] = H[r * HID + t];
    hr[t + 64] = H[r * HID + t + 64];
    __syncthreads();
    if (t < OUTC) {
        float acc = b[t];
        for (int k = 0; k < HID; k++) acc += hr[k] * W[k * OUTC + t];
        logits[t] = acc;
    }
    __syncthreads();
    if (t == 0) {
        float m = logits[0];
        for (int o = 1; o < OUTC; o++) m = fmaxf(m, logits[o]);
        float sum = 0.f;
        for (int o = 0; o < OUTC; o++) sum += expf(logits[o] - m);
        mstat[0] = m;
        mstat[1] = logf(sum);
    }
    __syncthreads();
    if (t < OUTC) out[r * OUTC + t] = logits[t] - mstat[0] - mstat[1];
}

extern "C" void kernel_launch(void* const* d_in, const int* in_sizes, int n_in,
                              void* d_out, int out_size, void* d_ws, size_t ws_size,
                              hipStream_t stream) {
    const float* n_feat = (const float*)d_in[0];
    const int*   src    = (const int*)d_in[1];
    const int*   dst    = (const int*)d_in[2];
    const int*   gid    = (const int*)d_in[3];
    const float* W1     = (const float*)d_in[4];
    const float* b1     = (const float*)d_in[5];
    const float* W2     = (const float*)d_in[6];
    const float* b2     = (const float*)d_in[7];
    const float* gamma  = (const float*)d_in[8];
    const float* beta   = (const float*)d_in[9];
    const float* fc1_w  = (const float*)d_in[10];
    const float* fc1_b  = (const float*)d_in[11];
    const float* fc2_w  = (const float*)d_in[12];
    const float* fc2_b  = (const float*)d_in[13];

    char* wsb = (char*)d_ws;
    size_t off = 0;
    auto alloc = [&](size_t bytes) -> void* {
        void* p = wsb + off;
        off += (bytes + 255) & ~(size_t)255;
        return p;
    };
    int*   cnt_in  = (int*)alloc((size_t)N_NODES * 4);
    int*   row_ptr = (int*)alloc((size_t)(N_NODES + 1) * 4);
    int*   wr_off  = (int*)alloc((size_t)(N_NODES + 1) * 4);
    int*   e_src   = (int*)alloc((size_t)E_SRC_CAP * 4);
    float* inv_out = (float*)alloc((size_t)N_NODES * 4);
    float* inv_in  = (float*)alloc((size_t)N_NODES * 4);
    // ybuf doubles as: partial histograms (2*HB*HWORDS u32 = 16 MB), then bf16 Y incl. dummy row
    void*  ybuf    = alloc((size_t)2 * HB * HWORDS * 4);
    float* X       = (float*)alloc((size_t)N_NODES * HID * 4);
    float* scale   = (float*)alloc(HID * 4);
    float* shift   = (float*)alloc(HID * 4);
    float* H       = (float*)alloc((size_t)N_GRAPHS * HID * 4);
    int*   bsum    = (int*)alloc((size_t)SCAN_B * 4);
    int*   boff    = (int*)alloc((size_t)SCAN_B * 4);

    unsigned int*   part = (unsigned int*)ybuf;
    __hip_bfloat16* Y    = (__hip_bfloat16*)ybuf;  // (N_NODES+1) x HID bf16 = 12.8 MB + 256 B

    float* emb_out = (float*)d_out;                // [128,128]
    float* lsm_out = emb_out + N_GRAPHS * HID;     // [128,10]

    hipMemsetAsync(emb_out, 0, (size_t)N_GRAPHS * HID * 4, stream);

    hist_part_kernel<<<2 * HB, 1024, 0, stream>>>(src, dst, part);
    hist_reduce_kernel<<<(HWORDS + 255) / 256, 256, 0, stream>>>(part, cnt_in, inv_out, inv_in);
    scan_sum_kernel<<<N_SCAN_BLOCKS, SCAN_B, 0, stream>>>(cnt_in, bsum);
    scan_bsum_kernel<<<1, SCAN_B, 0, stream>>>(bsum, boff);
    scan_write_kernel<<<N_SCAN_BLOCKS, SCAN_B, 0, stream>>>(cnt_in, boff, row_ptr, wr_off);
    csr_fill_kernel<<<(N_EDGES + 255) / 256, 256, 0, stream>>>(src, dst, wr_off, e_src);
    fill_pad_kernel<<<(N_NODES + 255) / 256, 256, 0, stream>>>(row_ptr, cnt_in, e_src);

    // layer 1
    matmul_kernel<<<(N_NODES + 63) / 64, 256, 0, stream>>>(n_feat, inv_out, W1, Y);
    agg_kernel<<<(N_NODES + 3) / 4, 256, 0, stream>>>(Y, e_src, row_ptr, inv_in, b1, X);
    // layer 2
    matmul_kernel<<<(N_NODES + 63) / 64, 256, 0, stream>>>(X, inv_out, W2, Y);
    agg_kernel<<<(N_NODES + 3) / 4, 256, 0, stream>>>(Y, e_src, row_ptr, inv_in, b2, X);

    // pooling -> embedding output
    pool_kernel<<<N_POOL_BLOCKS, 64, 0, stream>>>(X, gid, emb_out);
    // head
    bnstats_kernel<<<1, HID, 0, stream>>>(emb_out, gamma, beta, scale, shift);
    fc1_kernel<<<N_GRAPHS, HID, 0, stream>>>(emb_out, scale, shift, fc1_w, fc1_b, H);
    head_kernel<<<N_GRAPHS, 64, 0, stream>>>(H, fc2_w, fc2_b, lsm_out);
}

// Round 7
// 303.283 us; speedup vs baseline: 2.1211x; 1.0566x over previous
//
#include <hip/hip_runtime.h>
#include <hip/hip_bf16.h>
#include <math.h>

#define N_NODES 50000
#define N_EDGES 800000
#define HID 128
#define N_GRAPHS 128
#define OUTC 10
#define BN_EPS 1e-5f

#define SCAN_B 256
#define N_SCAN_BLOCKS ((N_NODES + SCAN_B - 1) / SCAN_B)  // 196

#define POOL_CHUNK 32
#define N_POOL_BLOCKS ((N_NODES + POOL_CHUNK - 1) / POOL_CHUNK)  // 1563

#define HB 80                 // histogram blocks per index array
#define HWORDS (N_NODES / 2)  // 25000 packed u32 words (2 x u16 bins)

#define EPAD 8                // CSR row padding (edges), multiple of 8 for guard-free inner loop
#define E_SRC_CAP (N_EDGES + N_NODES * EPAD)  // worst-case padded edge slots

// ---------------- LDS partial histograms (no global atomics) ----------------
__global__ __launch_bounds__(1024) void hist_part_kernel(const int* __restrict__ src,
                                                         const int* __restrict__ dst,
                                                         unsigned int* __restrict__ part) {
    __shared__ unsigned int h[HWORDS];  // 100 KB
    for (int i = threadIdx.x; i < HWORDS; i += 1024) h[i] = 0;
    __syncthreads();
    int half = (blockIdx.x >= HB) ? 1 : 0;
    const int* __restrict__ idx = half ? dst : src;
    int b = blockIdx.x - half * HB;
    for (int e = b * 1024 + threadIdx.x; e < N_EDGES; e += HB * 1024) {
        int v = idx[e];
        atomicAdd(&h[v >> 1], 1u << ((v & 1) << 4));  // LDS atomic, CU-local
    }
    __syncthreads();
    unsigned int* __restrict__ out = part + (size_t)blockIdx.x * HWORDS;
    for (int i = threadIdx.x; i < HWORDS; i += 1024) out[i] = h[i];
}

// Sum partials -> cnt_in / inv_out / inv_in. ALSO converts the dst half of `part`
// in place to per-(block,node) EXCLUSIVE prefixes (for atomic-free CSR fill).
__global__ void hist_reduce_kernel(unsigned int* __restrict__ part,
                                   int* __restrict__ cnt_in,
                                   float* __restrict__ inv_out, float* __restrict__ inv_in) {
    int w = blockIdx.x * blockDim.x + threadIdx.x;
    if (w >= HWORDS) return;
    unsigned int s = 0, d = 0;
    for (int b = 0; b < HB; b++) {
        s += part[(size_t)b * HWORDS + w];
        unsigned int c = part[(size_t)(b + HB) * HWORDS + w];
        part[(size_t)(b + HB) * HWORDS + w] = d;  // exclusive prefix over blocks
        d += c;
    }
    int i0 = w * 2, i1 = i0 + 1;
    int so0 = (int)(s & 0xFFFFu), so1 = (int)(s >> 16);
    int di0 = (int)(d & 0xFFFFu), di1 = (int)(d >> 16);
    cnt_in[i0] = di0;
    cnt_in[i1] = di1;
    inv_out[i0] = rsqrtf(fmaxf((float)so0, 1.0f));
    inv_out[i1] = rsqrtf(fmaxf((float)so1, 1.0f));
    inv_in[i0] = rsqrtf(fmaxf((float)di0, 1.0f));
    inv_in[i1] = rsqrtf(fmaxf((float)di1, 1.0f));
}

// ---------------- 3-phase exclusive scan over PADDED in-degrees ----------------
__global__ void scan_sum_kernel(const int* __restrict__ cnt, int* __restrict__ bsum) {
    int i = blockIdx.x * SCAN_B + threadIdx.x;
    int v = (i < N_NODES) ? ((cnt[i] + EPAD - 1) & ~(EPAD - 1)) : 0;
#pragma unroll
    for (int o = 32; o > 0; o >>= 1) v += __shfl_down(v, o);
    __shared__ int ws[4];
    int wave = threadIdx.x >> 6, lane = threadIdx.x & 63;
    if (lane == 0) ws[wave] = v;
    __syncthreads();
    if (threadIdx.x == 0) bsum[blockIdx.x] = ws[0] + ws[1] + ws[2] + ws[3];
}

__global__ void scan_bsum_kernel(const int* __restrict__ bsum, int* __restrict__ boff) {
    __shared__ int part[SCAN_B];
    int t = threadIdx.x;
    int v = (t < N_SCAN_BLOCKS) ? bsum[t] : 0;
    part[t] = v;
    __syncthreads();
    for (int off = 1; off < SCAN_B; off <<= 1) {
        int u = (t >= off) ? part[t - off] : 0;
        __syncthreads();
        part[t] += u;
        __syncthreads();
    }
    boff[t] = part[t] - v;
}

__global__ void scan_write_kernel(const int* __restrict__ cnt, const int* __restrict__ boff,
                                  int* __restrict__ row_ptr) {
    __shared__ int part[SCAN_B];
    int t = threadIdx.x;
    int i = blockIdx.x * SCAN_B + t;
    int v = (i < N_NODES) ? ((cnt[i] + EPAD - 1) & ~(EPAD - 1)) : 0;
    part[t] = v;
    __syncthreads();
    for (int off = 1; off < SCAN_B; off <<= 1) {
        int u = (t >= off) ? part[t - off] : 0;
        __syncthreads();
        part[t] += u;
        __syncthreads();
    }
    if (i < N_NODES) {
        int ex = part[t] - v + boff[blockIdx.x];
        row_ptr[i] = ex;
        if (i == N_NODES - 1) row_ptr[N_NODES] = ex + v;  // padded total
    }
}

// ---------------- CSR fill, atomic-free: LDS slot counters seeded with per-block prefixes ----
// Same block<->edge partition as hist_part's dst half.
__global__ __launch_bounds__(1024) void csr_fill_kernel(const int* __restrict__ src,
                                                        const int* __restrict__ dst,
                                                        const unsigned int* __restrict__ part,
                                                        const int* __restrict__ row_ptr,
                                                        int* __restrict__ edge_src) {
    __shared__ unsigned int loc[HWORDS];  // 100 KB: packed u16 running intra-bucket slots
    int b = blockIdx.x;
    const unsigned int* __restrict__ off = part + (size_t)(b + HB) * HWORDS;
    for (int i = threadIdx.x; i < HWORDS; i += 1024) loc[i] = off[i];
    __syncthreads();
    for (int e = b * 1024 + threadIdx.x; e < N_EDGES; e += HB * 1024) {
        int d = dst[e];
        unsigned int old = atomicAdd(&loc[d >> 1], 1u << ((d & 1) << 4));  // LDS atomic
        int local = (d & 1) ? (int)(old >> 16) : (int)(old & 0xFFFFu);
        edge_src[row_ptr[d] + local] = src[e];  // plain scattered store
    }
}

// fill padded slots with the dummy zero-row index N_NODES
__global__ void fill_pad_kernel(const int* __restrict__ row_ptr, const int* __restrict__ cnt,
                                int* __restrict__ edge_src) {
    int n = blockIdx.x * blockDim.x + threadIdx.x;
    if (n < N_NODES) {
        int p = row_ptr[n] + cnt[n];
        int e = row_ptr[n + 1];
        for (; p < e; p++) edge_src[p] = N_NODES;
    }
}

// ---------------- Y[r][:] = bf16( (scale[r]*X[r][:]) @ W )  (fp32 compute) ----------------
// Also emits the all-zero dummy row r == N_NODES (X-tile guard zero-fills it).
__global__ __launch_bounds__(256) void matmul_kernel(const float* __restrict__ X,
                                                     const float* __restrict__ scale,
                                                     const float* __restrict__ W,
                                                     __hip_bfloat16* __restrict__ Y) {
    __shared__ float xs[64 * HID];   // 32 KB
    __shared__ float wsh[32 * HID];  // 16 KB
    int tid = threadIdx.x;
    int row0 = blockIdx.x * 64;

    for (int j = 0; j < 8; j++) {
        int idx = (j * 256 + tid) * 4;
        int r = row0 + (idx >> 7);
        float4 v = make_float4(0.f, 0.f, 0.f, 0.f);
        if (r < N_NODES) {
            v = *(const float4*)&X[(size_t)r * HID + (idx & 127)];
            float sc = scale[r];
            v.x *= sc; v.y *= sc; v.z *= sc; v.w *= sc;
        }
        *(float4*)&xs[idx] = v;
    }

    int cx = tid & 31;
    int ry = tid >> 5;
    float acc[8][4] = {};

    for (int kt = 0; kt < HID; kt += 32) {
        __syncthreads();
        for (int j = 0; j < 4; j++) {
            int idx = (j * 256 + tid) * 4;
            *(float4*)&wsh[idx] = *(const float4*)&W[kt * HID + idx];
        }
        __syncthreads();
        for (int k = 0; k < 32; k += 4) {
            float4 w0 = *(float4*)&wsh[(k + 0) * HID + cx * 4];
            float4 w1 = *(float4*)&wsh[(k + 1) * HID + cx * 4];
            float4 w2 = *(float4*)&wsh[(k + 2) * HID + cx * 4];
            float4 w3 = *(float4*)&wsh[(k + 3) * HID + cx * 4];
#pragma unroll
            for (int i = 0; i < 8; i++) {
                const float4 xv = *(float4*)&xs[(ry * 8 + i) * HID + kt + k];
                acc[i][0] += xv.x * w0.x + xv.y * w1.x + xv.z * w2.x + xv.w * w3.x;
                acc[i][1] += xv.x * w0.y + xv.y * w1.y + xv.z * w2.y + xv.w * w3.y;
                acc[i][2] += xv.x * w0.z + xv.y * w1.z + xv.z * w2.z + xv.w * w3.z;
                acc[i][3] += xv.x * w0.w + xv.y * w1.w + xv.z * w2.w + xv.w * w3.w;
            }
        }
    }

#pragma unroll
    for (int i = 0; i < 8; i++) {
        int r = row0 + ry * 8 + i;
        if (r < N_NODES + 1) {  // include dummy zero row
            ushort4 o;
            o.x = __hip_bfloat16_raw(__float2bfloat16(acc[i][0])).x;
            o.y = __hip_bfloat16_raw(__float2bfloat16(acc[i][1])).x;
            o.z = __hip_bfloat16_raw(__float2bfloat16(acc[i][2])).x;
            o.w = __hip_bfloat16_raw(__float2bfloat16(acc[i][3])).x;
            *(ushort4*)&Y[(size_t)r * HID + cx * 4] = o;
        }
    }
}

// ---------------- CSR gather-accumulate over bf16 Y (fp32 accumulate) ----------------
__global__ __launch_bounds__(256) void agg_kernel(const __hip_bfloat16* __restrict__ Y,
                                                  const int* __restrict__ edge_src,
                                                  const int* __restrict__ row_ptr,
                                                  const float* __restrict__ inv_in,
                                                  const float* __restrict__ bias,
                                                  float* __restrict__ Xout) {
    const uint4* __restrict__ Yq = (const uint4*)Y;  // 8 bf16 per uint4
    int wave = threadIdx.x >> 6;
    int lane = threadIdx.x & 63;
    int n = blockIdx.x * 4 + wave;
    if (n >= N_NODES) return;
    int beg = row_ptr[n], end = row_ptr[n + 1];  // length multiple of 8
    int esub = lane >> 4;   // which of 4 concurrent edges
    int f16  = lane & 15;   // feature quad: feats f16*8 .. f16*8+7
    float acc[8] = {};
    for (int base = beg; base < end; base += 64) {
        int m = min(64, end - base);  // multiple of 8
        int idx = (lane < m) ? edge_src[base + lane] : N_NODES;
        for (int j = 0; j < m; j += 8) {
            int s0 = __shfl(idx, j + esub);
            int s1 = __shfl(idx, j + 4 + esub);
            uint4 u0 = Yq[s0 * (HID / 8) + f16];
            uint4 u1 = Yq[s1 * (HID / 8) + f16];
            acc[0] += __uint_as_float(u0.x << 16); acc[1] += __uint_as_float(u0.x & 0xFFFF0000u);
            acc[2] += __uint_as_float(u0.y << 16); acc[3] += __uint_as_float(u0.y & 0xFFFF0000u);
            acc[4] += __uint_as_float(u0.z << 16); acc[5] += __uint_as_float(u0.z & 0xFFFF0000u);
            acc[6] += __uint_as_float(u0.w << 16); acc[7] += __uint_as_float(u0.w & 0xFFFF0000u);
            acc[0] += __uint_as_float(u1.x << 16); acc[1] += __uint_as_float(u1.x & 0xFFFF0000u);
            acc[2] += __uint_as_float(u1.y << 16); acc[3] += __uint_as_float(u1.y & 0xFFFF0000u);
            acc[4] += __uint_as_float(u1.z << 16); acc[5] += __uint_as_float(u1.z & 0xFFFF0000u);
            acc[6] += __uint_as_float(u1.w << 16); acc[7] += __uint_as_float(u1.w & 0xFFFF0000u);
        }
    }
#pragma unroll
    for (int i = 0; i < 8; i++) {
        acc[i] += __shfl_xor(acc[i], 16);
        acc[i] += __shfl_xor(acc[i], 32);
    }
    if (lane < 16) {
        float si = inv_in[n];
        int f0 = f16 * 8;
        float4 b0 = *(const float4*)&bias[f0];
        float4 b1 = *(const float4*)&bias[f0 + 4];
        float4 o0, o1;
        o0.x = fmaxf(acc[0] * si + b0.x, 0.f);
        o0.y = fmaxf(acc[1] * si + b0.y, 0.f);
        o0.z = fmaxf(acc[2] * si + b0.z, 0.f);
        o0.w = fmaxf(acc[3] * si + b0.w, 0.f);
        o1.x = fmaxf(acc[4] * si + b1.x, 0.f);
        o1.y = fmaxf(acc[5] * si + b1.y, 0.f);
        o1.z = fmaxf(acc[6] * si + b1.z, 0.f);
        o1.w = fmaxf(acc[7] * si + b1.w, 0.f);
        *(float4*)&Xout[(size_t)n * HID + f0] = o0;
        *(float4*)&Xout[(size_t)n * HID + f0 + 4] = o1;
    }
}

// ---------------- SumPooling: chunked segment-sum over sorted gid ----------------
__global__ __launch_bounds__(64) void pool_kernel(const float* __restrict__ X,
                                                  const int* __restrict__ gid,
                                                  float* __restrict__ emb) {
    int lane = threadIdx.x;
    int n0 = blockIdx.x * POOL_CHUNK;
    int n1 = min(n0 + POOL_CHUNK, N_NODES);
    if (n0 >= N_NODES) return;
    int g_cur = gid[n0];
    float ax = 0.f, ay = 0.f;
    for (int n = n0; n < n1; n++) {
        int g = gid[n];
        if (g != g_cur) {
            atomicAdd(&emb[g_cur * HID + lane * 2], ax);
            atomicAdd(&emb[g_cur * HID + lane * 2 + 1], ay);
            ax = 0.f; ay = 0.f;
            g_cur = g;
        }
        float2 v = *(const float2*)&X[(size_t)n * HID + lane * 2];
        ax += v.x;
        ay += v.y;
    }
    atomicAdd(&emb[g_cur * HID + lane * 2], ax);
    atomicAdd(&emb[g_cur * HID + lane * 2 + 1], ay);
}

// ---------------- BatchNorm batch stats ----------------
__global__ void bnstats_kernel(const float* __restrict__ emb, const float* __restrict__ gamma,
                               const float* __restrict__ beta, float* __restrict__ scale,
                               float* __restrict__ shift) {
    int f = threadIdx.x;  // 128
    float s = 0.f;
    for (int r = 0; r < N_GRAPHS; r++) s += emb[r * HID + f];
    float mu = s * (1.f / N_GRAPHS);
    float v = 0.f;
    for (int r = 0; r < N_GRAPHS; r++) {
        float d = emb[r * HID + f] - mu;
        v += d * d;
    }
    v *= (1.f / N_GRAPHS);
    float sc = gamma[f] * rsqrtf(v + BN_EPS);
    scale[f] = sc;
    shift[f] = beta[f] - mu * sc;
}

// ---------------- fc1 ----------------
__global__ void fc1_kernel(const float* __restrict__ emb, const float* __restrict__ scale,
                           const float* __restrict__ shift, const float* __restrict__ W,
                           const float* __restrict__ b, float* __restrict__ H) {
    __shared__ float xr[HID];
    int r = blockIdx.x, c = threadIdx.x;  // 128 threads
    xr[c] = emb[r * HID + c] * scale[c] + shift[c];
    __syncthreads();
    float acc = b[c];
    for (int k = 0; k < HID; k++) acc += xr[k] * W[k * HID + c];
    H[r * HID + c] = fmaxf(acc, 0.f);
}

// ---------------- fc2 + log_softmax ----------------
__global__ void head_kernel(const float* __restrict__ H, const float* __restrict__ W,
                            const float* __restrict__ b, float* __restrict__ out) {
    __shared__ float hr[HID];
    __shared__ float logits[OUTC];
    __shared__ float mstat[2];
    int r = blockIdx.x, t = threadIdx.x;  // 64 threads
    hr[t] = H[r * HID + t];
    hr[t + 64] = H[r * HID + t + 64];
    __syncthreads();
    if (t < OUTC) {
        float acc = b[t];
        for (int k = 0; k < HID; k++) acc += hr[k] * W[k * OUTC + t];
        logits[t] = acc;
    }
    __syncthreads();
    if (t == 0) {
        float m = logits[0];
        for (int o = 1; o < OUTC; o++) m = fmaxf(m, logits[o]);
        float sum = 0.f;
        for (int o = 0; o < OUTC; o++) sum += expf(logits[o] - m);
        mstat[0] = m;
        mstat[1] = logf(sum);
    }
    __syncthreads();
    if (t < OUTC) out[r * OUTC + t] = logits[t] - mstat[0] - mstat[1];
}

extern "C" void kernel_launch(void* const* d_in, const int* in_sizes, int n_in,
                              void* d_out, int out_size, void* d_ws, size_t ws_size,
                              hipStream_t stream) {
    const float* n_feat = (const float*)d_in[0];
    const int*   src    = (const int*)d_in[1];
    const int*   dst    = (const int*)d_in[2];
    const int*   gid    = (const int*)d_in[3];
    const float* W1     = (const float*)d_in[4];
    const float* b1     = (const float*)d_in[5];
    const float* W2     = (const float*)d_in[6];
    const float* b2     = (const float*)d_in[7];
    const float* gamma  = (const float*)d_in[8];
    const float* beta   = (const float*)d_in[9];
    const float* fc1_w  = (const float*)d_in[10];
    const float* fc1_b  = (const float*)d_in[11];
    const float* fc2_w  = (const float*)d_in[12];
    const float* fc2_b  = (const float*)d_in[13];

    char* wsb = (char*)d_ws;
    size_t off = 0;
    auto alloc = [&](size_t bytes) -> void* {
        void* p = wsb + off;
        off += (bytes + 255) & ~(size_t)255;
        return p;
    };
    int*   cnt_in  = (int*)alloc((size_t)N_NODES * 4);
    int*   row_ptr = (int*)alloc((size_t)(N_NODES + 1) * 4);
    int*   e_src   = (int*)alloc((size_t)E_SRC_CAP * 4);
    float* inv_out = (float*)alloc((size_t)N_NODES * 4);
    float* inv_in  = (float*)alloc((size_t)N_NODES * 4);
    // ybuf doubles as: partial histograms (2*HB*HWORDS u32 = 16 MB), then bf16 Y incl. dummy row
    void*  ybuf    = alloc((size_t)2 * HB * HWORDS * 4);
    float* X       = (float*)alloc((size_t)N_NODES * HID * 4);
    float* scale   = (float*)alloc(HID * 4);
    float* shift   = (float*)alloc(HID * 4);
    float* H       = (float*)alloc((size_t)N_GRAPHS * HID * 4);
    int*   bsum    = (int*)alloc((size_t)SCAN_B * 4);
    int*   boff    = (int*)alloc((size_t)SCAN_B * 4);

    unsigned int*   part = (unsigned int*)ybuf;
    __hip_bfloat16* Y    = (__hip_bfloat16*)ybuf;  // (N_NODES+1) x HID bf16 = 12.8 MB + 256 B

    float* emb_out = (float*)d_out;                // [128,128]
    float* lsm_out = emb_out + N_GRAPHS * HID;     // [128,10]

    hipMemsetAsync(emb_out, 0, (size_t)N_GRAPHS * HID * 4, stream);

    hist_part_kernel<<<2 * HB, 1024, 0, stream>>>(src, dst, part);
    hist_reduce_kernel<<<(HWORDS + 255) / 256, 256, 0, stream>>>(part, cnt_in, inv_out, inv_in);
    scan_sum_kernel<<<N_SCAN_BLOCKS, SCAN_B, 0, stream>>>(cnt_in, bsum);
    scan_bsum_kernel<<<1, SCAN_B, 0, stream>>>(bsum, boff);
    scan_write_kernel<<<N_SCAN_BLOCKS, SCAN_B, 0, stream>>>(cnt_in, boff, row_ptr);
    csr_fill_kernel<<<HB, 1024, 0, stream>>>(src, dst, part, row_ptr, e_src);
    fill_pad_kernel<<<(N_NODES + 255) / 256, 256, 0, stream>>>(row_ptr, cnt_in, e_src);

    // layer 1
    matmul_kernel<<<(N_NODES + 63) / 64, 256, 0, stream>>>(n_feat, inv_out, W1, Y);
    agg_kernel<<<(N_NODES + 3) / 4, 256, 0, stream>>>(Y, e_src, row_ptr, inv_in, b1, X);
    // layer 2
    matmul_kernel<<<(N_NODES + 63) / 64, 256, 0, stream>>>(X, inv_out, W2, Y);
    agg_kernel<<<(N_NODES + 3) / 4, 256, 0, stream>>>(Y, e_src, row_ptr, inv_in, b2, X);

    // pooling -> embedding output
    pool_kernel<<<N_POOL_BLOCKS, 64, 0, stream>>>(X, gid, emb_out);
    // head
    bnstats_kernel<<<1, HID, 0, stream>>>(emb_out, gamma, beta, scale, shift);
    fc1_kernel<<<N_GRAPHS, HID, 0, stream>>>(emb_out, scale, shift, fc1_w, fc1_b, H);
    head_kernel<<<N_GRAPHS, 64, 0, stream>>>(H, fc2_w, fc2_b, lsm_out);
}

// Round 8
// 261.331 us; speedup vs baseline: 2.4616x; 1.1605x over previous
//
#include <hip/hip_runtime.h>
#include <hip/hip_bf16.h>
#include <math.h>

#define N_NODES 50000
#define N_EDGES 800000
#define HID 128
#define N_GRAPHS 128
#define OUTC 10
#define BN_EPS 1e-5f

#define SCAN_B 256
#define N_SCAN_BLOCKS ((N_NODES + SCAN_B - 1) / SCAN_B)  // 196

#define POOL_CHUNK 32
#define N_POOL_BLOCKS ((N_NODES + POOL_CHUNK - 1) / POOL_CHUNK)  // 1563

#define HB 80                 // histogram blocks per index array
#define HWORDS (N_NODES / 2)  // 25000 packed u32 words (2 x u16 bins)

#define EPAD 8                // CSR row padding (edges), multiple of 8 for guard-free inner loop
#define E_SRC_CAP (N_EDGES + N_NODES * EPAD)  // worst-case padded edge slots

#define LDA 136               // LDS row stride (ushorts): 272 B = 17*16B -> aligned b128, 2-way banks

typedef short short8 __attribute__((ext_vector_type(8)));
typedef float floatx4 __attribute__((ext_vector_type(4)));

template <typename T, typename F>
__device__ inline T bitcast(F f) {
    union { F a; T b; } u;
    u.a = f;
    return u.b;
}

// ---------------- LDS partial histograms (no global atomics) ----------------
__global__ __launch_bounds__(1024) void hist_part_kernel(const int* __restrict__ src,
                                                         const int* __restrict__ dst,
                                                         unsigned int* __restrict__ part) {
    __shared__ unsigned int h[HWORDS];  // 100 KB
    for (int i = threadIdx.x; i < HWORDS; i += 1024) h[i] = 0;
    __syncthreads();
    int half = (blockIdx.x >= HB) ? 1 : 0;
    const int* __restrict__ idx = half ? dst : src;
    int b = blockIdx.x - half * HB;
    for (int e = b * 1024 + threadIdx.x; e < N_EDGES; e += HB * 1024) {
        int v = idx[e];
        atomicAdd(&h[v >> 1], 1u << ((v & 1) << 4));  // LDS atomic, CU-local
    }
    __syncthreads();
    unsigned int* __restrict__ out = part + (size_t)blockIdx.x * HWORDS;
    for (int i = threadIdx.x; i < HWORDS; i += 1024) out[i] = h[i];
}

// Sum partials -> cnt_in / inv_out / inv_in. ALSO converts the dst half of `part`
// in place to per-(block,node) EXCLUSIVE prefixes (for atomic-free CSR fill).
__global__ void hist_reduce_kernel(unsigned int* __restrict__ part,
                                   int* __restrict__ cnt_in,
                                   float* __restrict__ inv_out, float* __restrict__ inv_in) {
    int w = blockIdx.x * blockDim.x + threadIdx.x;
    if (w >= HWORDS) return;
    unsigned int s = 0, d = 0;
    for (int b = 0; b < HB; b++) {
        s += part[(size_t)b * HWORDS + w];
        unsigned int c = part[(size_t)(b + HB) * HWORDS + w];
        part[(size_t)(b + HB) * HWORDS + w] = d;  // exclusive prefix over blocks
        d += c;
    }
    int i0 = w * 2, i1 = i0 + 1;
    int so0 = (int)(s & 0xFFFFu), so1 = (int)(s >> 16);
    int di0 = (int)(d & 0xFFFFu), di1 = (int)(d >> 16);
    cnt_in[i0] = di0;
    cnt_in[i1] = di1;
    inv_out[i0] = rsqrtf(fmaxf((float)so0, 1.0f));
    inv_out[i1] = rsqrtf(fmaxf((float)so1, 1.0f));
    inv_in[i0] = rsqrtf(fmaxf((float)di0, 1.0f));
    inv_in[i1] = rsqrtf(fmaxf((float)di1, 1.0f));
}

// ---------------- 3-phase exclusive scan over PADDED in-degrees ----------------
__global__ void scan_sum_kernel(const int* __restrict__ cnt, int* __restrict__ bsum) {
    int i = blockIdx.x * SCAN_B + threadIdx.x;
    int v = (i < N_NODES) ? ((cnt[i] + EPAD - 1) & ~(EPAD - 1)) : 0;
#pragma unroll
    for (int o = 32; o > 0; o >>= 1) v += __shfl_down(v, o);
    __shared__ int ws[4];
    int wave = threadIdx.x >> 6, lane = threadIdx.x & 63;
    if (lane == 0) ws[wave] = v;
    __syncthreads();
    if (threadIdx.x == 0) bsum[blockIdx.x] = ws[0] + ws[1] + ws[2] + ws[3];
}

__global__ void scan_bsum_kernel(const int* __restrict__ bsum, int* __restrict__ boff) {
    __shared__ int part[SCAN_B];
    int t = threadIdx.x;
    int v = (t < N_SCAN_BLOCKS) ? bsum[t] : 0;
    part[t] = v;
    __syncthreads();
    for (int off = 1; off < SCAN_B; off <<= 1) {
        int u = (t >= off) ? part[t - off] : 0;
        __syncthreads();
        part[t] += u;
        __syncthreads();
    }
    boff[t] = part[t] - v;
}

__global__ void scan_write_kernel(const int* __restrict__ cnt, const int* __restrict__ boff,
                                  int* __restrict__ row_ptr) {
    __shared__ int part[SCAN_B];
    int t = threadIdx.x;
    int i = blockIdx.x * SCAN_B + t;
    int v = (i < N_NODES) ? ((cnt[i] + EPAD - 1) & ~(EPAD - 1)) : 0;
    part[t] = v;
    __syncthreads();
    for (int off = 1; off < SCAN_B; off <<= 1) {
        int u = (t >= off) ? part[t - off] : 0;
        __syncthreads();
        part[t] += u;
        __syncthreads();
    }
    if (i < N_NODES) {
        int ex = part[t] - v + boff[blockIdx.x];
        row_ptr[i] = ex;
        if (i == N_NODES - 1) row_ptr[N_NODES] = ex + v;  // padded total
    }
}

// ---------------- CSR fill, atomic-free ----------------
__global__ __launch_bounds__(1024) void csr_fill_kernel(const int* __restrict__ src,
                                                        const int* __restrict__ dst,
                                                        const unsigned int* __restrict__ part,
                                                        const int* __restrict__ row_ptr,
                                                        int* __restrict__ edge_src) {
    __shared__ unsigned int loc[HWORDS];  // 100 KB: packed u16 running intra-bucket slots
    int b = blockIdx.x;
    const unsigned int* __restrict__ off = part + (size_t)(b + HB) * HWORDS;
    for (int i = threadIdx.x; i < HWORDS; i += 1024) loc[i] = off[i];
    __syncthreads();
    for (int e = b * 1024 + threadIdx.x; e < N_EDGES; e += HB * 1024) {
        int d = dst[e];
        unsigned int old = atomicAdd(&loc[d >> 1], 1u << ((d & 1) << 4));  // LDS atomic
        int local = (d & 1) ? (int)(old >> 16) : (int)(old & 0xFFFFu);
        edge_src[row_ptr[d] + local] = src[e];  // plain scattered store
    }
}

// fill padded slots with the dummy zero-row index N_NODES
__global__ void fill_pad_kernel(const int* __restrict__ row_ptr, const int* __restrict__ cnt,
                                int* __restrict__ edge_src) {
    int n = blockIdx.x * blockDim.x + threadIdx.x;
    if (n < N_NODES) {
        int p = row_ptr[n] + cnt[n];
        int e = row_ptr[n + 1];
        for (; p < e; p++) edge_src[p] = N_NODES;
    }
}

// ---------------- pack W (fp32 row-major [128][128]) into MFMA B-fragment order, bf16 ----
// B-frag for 16x16x32: lane holds B[k = quad*8+j][n = lane&15], j in [0,8).
// Wp layout: tile (kc,nt) -> 64 lanes -> 8 bf16 (one uint4 per lane).
__global__ __launch_bounds__(64) void wpack_kernel(const float* __restrict__ W1,
                                                   const float* __restrict__ W2,
                                                   unsigned short* __restrict__ Wp) {
    int b = blockIdx.x;           // 64 blocks: 32 tiles x 2 matrices
    int wi = b >> 5;
    const float* __restrict__ W = wi ? W2 : W1;
    int t = b & 31;
    int kc = t >> 3, nt = t & 7;
    int lane = threadIdx.x;
    int n = lane & 15, quad = lane >> 4;
    unsigned short v[8];
#pragma unroll
    for (int j = 0; j < 8; j++) {
        int k = kc * 32 + quad * 8 + j;
        v[j] = __hip_bfloat16_raw(__float2bfloat16(W[k * HID + nt * 16 + n])).x;
    }
    unsigned short* out = Wp + ((size_t)wi * 32 * 64 + (size_t)(kc * 8 + nt) * 64 + lane) * 8;
    *(uint4*)out = *(uint4*)v;
}

// ---------------- Y[r][:] = bf16( (scale[r]*X[r][:]) @ W )  via MFMA bf16 ----------------
// block: 64 rows x 128 cols, 4 waves x (16 rows x 128 cols); emits dummy zero row N_NODES.
__global__ __launch_bounds__(256) void matmul_kernel(const float* __restrict__ X,
                                                     const float* __restrict__ scale,
                                                     const unsigned short* __restrict__ Wp,
                                                     __hip_bfloat16* __restrict__ Y) {
    __shared__ unsigned short xs[64 * LDA];  // 17 KB bf16, padded rows
    int tid = threadIdx.x;
    int row0 = blockIdx.x * 64;

    // stage 64x128 fp32 -> scaled bf16 LDS (coalesced float4 loads)
    for (int j = 0; j < 8; j++) {
        int idx4 = j * 256 + tid;          // float4 index in 64x128 tile
        int r = idx4 >> 5;                 // local row
        int col = (idx4 & 31) * 4;
        int rg = row0 + r;
        float4 v = make_float4(0.f, 0.f, 0.f, 0.f);
        if (rg < N_NODES) {
            v = *(const float4*)&X[(size_t)rg * HID + col];
            float sc = scale[rg];
            v.x *= sc; v.y *= sc; v.z *= sc; v.w *= sc;
        }
        unsigned short o[4];
        o[0] = __hip_bfloat16_raw(__float2bfloat16(v.x)).x;
        o[1] = __hip_bfloat16_raw(__float2bfloat16(v.y)).x;
        o[2] = __hip_bfloat16_raw(__float2bfloat16(v.z)).x;
        o[3] = __hip_bfloat16_raw(__float2bfloat16(v.w)).x;
        *(ushort4*)&xs[r * LDA + col] = *(ushort4*)o;
    }
    __syncthreads();

    int wave = tid >> 6, lane = tid & 63;
    int m = lane & 15, quad = lane >> 4;
    int rowl = wave * 16;  // wave's 16-row slice within tile

    // A frags: a[kc] = A[m][kc*32 + quad*8 .. +8]
    short8 a[4];
#pragma unroll
    for (int kc = 0; kc < 4; kc++)
        a[kc] = bitcast<short8>(*(const uint4*)&xs[(rowl + m) * LDA + kc * 32 + quad * 8]);

    floatx4 acc[8];
#pragma unroll
    for (int nt = 0; nt < 8; nt++) acc[nt] = (floatx4){0.f, 0.f, 0.f, 0.f};

#pragma unroll
    for (int nt = 0; nt < 8; nt++) {
#pragma unroll
        for (int kc = 0; kc < 4; kc++) {
            short8 bfr = bitcast<short8>(
                *(const uint4*)&Wp[((size_t)(kc * 8 + nt) * 64 + lane) * 8]);
            acc[nt] = __builtin_amdgcn_mfma_f32_16x16x32_bf16(a[kc], bfr, acc[nt], 0, 0, 0);
        }
    }

    // C/D layout: col = lane&15, row = quad*4 + reg  [verified m89]
#pragma unroll
    for (int nt = 0; nt < 8; nt++) {
#pragma unroll
        for (int i = 0; i < 4; i++) {
            int rg = row0 + rowl + quad * 4 + i;
            if (rg < N_NODES + 1) {
                Y[(size_t)rg * HID + nt * 16 + m] = __float2bfloat16(acc[nt][i]);
            }
        }
    }
}

// ---------------- CSR gather-accumulate over bf16 Y (fp32 accumulate) ----------------
__global__ __launch_bounds__(256) void agg_kernel(const __hip_bfloat16* __restrict__ Y,
                                                  const int* __restrict__ edge_src,
                                                  const int* __restrict__ row_ptr,
                                                  const float* __restrict__ inv_in,
                                                  const float* __restrict__ bias,
                                                  float* __restrict__ Xout) {
    const uint4* __restrict__ Yq = (const uint4*)Y;  // 8 bf16 per uint4
    int wave = threadIdx.x >> 6;
    int lane = threadIdx.x & 63;
    int n = blockIdx.x * 4 + wave;
    if (n >= N_NODES) return;
    int beg = row_ptr[n], end = row_ptr[n + 1];  // length multiple of 8
    int esub = lane >> 4;   // which of 4 concurrent edges
    int f16  = lane & 15;   // feature quad: feats f16*8 .. f16*8+7
    float acc[8] = {};
    for (int base = beg; base < end; base += 64) {
        int mm = min(64, end - base);  // multiple of 8
        int idx = (lane < mm) ? edge_src[base + lane] : N_NODES;
        for (int j = 0; j < mm; j += 8) {
            int s0 = __shfl(idx, j + esub);
            int s1 = __shfl(idx, j + 4 + esub);
            uint4 u0 = Yq[s0 * (HID / 8) + f16];
            uint4 u1 = Yq[s1 * (HID / 8) + f16];
            acc[0] += __uint_as_float(u0.x << 16); acc[1] += __uint_as_float(u0.x & 0xFFFF0000u);
            acc[2] += __uint_as_float(u0.y << 16); acc[3] += __uint_as_float(u0.y & 0xFFFF0000u);
            acc[4] += __uint_as_float(u0.z << 16); acc[5] += __uint_as_float(u0.z & 0xFFFF0000u);
            acc[6] += __uint_as_float(u0.w << 16); acc[7] += __uint_as_float(u0.w & 0xFFFF0000u);
            acc[0] += __uint_as_float(u1.x << 16); acc[1] += __uint_as_float(u1.x & 0xFFFF0000u);
            acc[2] += __uint_as_float(u1.y << 16); acc[3] += __uint_as_float(u1.y & 0xFFFF0000u);
            acc[4] += __uint_as_float(u1.z << 16); acc[5] += __uint_as_float(u1.z & 0xFFFF0000u);
            acc[6] += __uint_as_float(u1.w << 16); acc[7] += __uint_as_float(u1.w & 0xFFFF0000u);
        }
    }
#pragma unroll
    for (int i = 0; i < 8; i++) {
        acc[i] += __shfl_xor(acc[i], 16);
        acc[i] += __shfl_xor(acc[i], 32);
    }
    if (lane < 16) {
        float si = inv_in[n];
        int f0 = f16 * 8;
        float4 b0 = *(const float4*)&bias[f0];
        float4 b1 = *(const float4*)&bias[f0 + 4];
        float4 o0, o1;
        o0.x = fmaxf(acc[0] * si + b0.x, 0.f);
        o0.y = fmaxf(acc[1] * si + b0.y, 0.f);
        o0.z = fmaxf(acc[2] * si + b0.z, 0.f);
        o0.w = fmaxf(acc[3] * si + b0.w, 0.f);
        o1.x = fmaxf(acc[4] * si + b1.x, 0.f);
        o1.y = fmaxf(acc[5] * si + b1.y, 0.f);
        o1.z = fmaxf(acc[6] * si + b1.z, 0.f);
        o1.w = fmaxf(acc[7] * si + b1.w, 0.f);
        *(float4*)&Xout[(size_t)n * HID + f0] = o0;
        *(float4*)&Xout[(size_t)n * HID + f0 + 4] = o1;
    }
}

// ---------------- SumPooling: chunked segment-sum over sorted gid ----------------
__global__ __launch_bounds__(64) void pool_kernel(const float* __restrict__ X,
                                                  const int* __restrict__ gid,
                                                  float* __restrict__ emb) {
    int lane = threadIdx.x;
    int n0 = blockIdx.x * POOL_CHUNK;
    int n1 = min(n0 + POOL_CHUNK, N_NODES);
    if (n0 >= N_NODES) return;
    int g_cur = gid[n0];
    float ax = 0.f, ay = 0.f;
    for (int n = n0; n < n1; n++) {
        int g = gid[n];
        if (g != g_cur) {
            atomicAdd(&emb[g_cur * HID + lane * 2], ax);
            atomicAdd(&emb[g_cur * HID + lane * 2 + 1], ay);
            ax = 0.f; ay = 0.f;
            g_cur = g;
        }
        float2 v = *(const float2*)&X[(size_t)n * HID + lane * 2];
        ax += v.x;
        ay += v.y;
    }
    atomicAdd(&emb[g_cur * HID + lane * 2], ax);
    atomicAdd(&emb[g_cur * HID + lane * 2 + 1], ay);
}

// ---------------- BatchNorm batch stats ----------------
__global__ void bnstats_kernel(const float* __restrict__ emb, const float* __restrict__ gamma,
                               const float* __restrict__ beta, float* __restrict__ scale,
                               float* __restrict__ shift) {
    int f = threadIdx.x;  // 128
    float s = 0.f;
    for (int r = 0; r < N_GRAPHS; r++) s += emb[r * HID + f];
    float mu = s * (1.f / N_GRAPHS);
    float v = 0.f;
    for (int r = 0; r < N_GRAPHS; r++) {
        float d = emb[r * HID + f] - mu;
        v += d * d;
    }
    v *= (1.f / N_GRAPHS);
    float sc = gamma[f] * rsqrtf(v + BN_EPS);
    scale[f] = sc;
    shift[f] = beta[f] - mu * sc;
}

// ---------------- fc1 ----------------
__global__ void fc1_kernel(const float* __restrict__ emb, const float* __restrict__ scale,
                           const float* __restrict__ shift, const float* __restrict__ W,
                           const float* __restrict__ b, float* __restrict__ H) {
    __shared__ float xr[HID];
    int r = blockIdx.x, c = threadIdx.x;  // 128 threads
    xr[c] = emb[r * HID + c] * scale[c] + shift[c];
    __syncthreads();
    float acc = b[c];
    for (int k = 0; k < HID; k++) acc += xr[k] * W[k * HID + c];
    H[r * HID + c] = fmaxf(acc, 0.f);
}

// ---------------- fc2 + log_softmax ----------------
__global__ void head_kernel(const float* __restrict__ H, const float* __restrict__ W,
                            const float* __restrict__ b, float* __restrict__ out) {
    __shared__ float hr[HID];
    __shared__ float logits[OUTC];
    __shared__ float mstat[2];
    int r = blockIdx.x, t = threadIdx.x;  // 64 threads
    hr[t] = H[r * HID + t];
    hr[t + 64] = H[r * HID + t + 64];
    __syncthreads();
    if (t < OUTC) {
        float acc = b[t];
        for (int k = 0; k < HID; k++) acc += hr[k] * W[k * OUTC + t];
        logits[t] = acc;
    }
    __syncthreads();
    if (t == 0) {
        float m = logits[0];
        for (int o = 1; o < OUTC; o++) m = fmaxf(m, logits[o]);
        float sum = 0.f;
        for (int o = 0; o < OUTC; o++) sum += expf(logits[o] - m);
        mstat[0] = m;
        mstat[1] = logf(sum);
    }
    __syncthreads();
    if (t < OUTC) out[r * OUTC + t] = logits[t] - mstat[0] - mstat[1];
}

extern "C" void kernel_launch(void* const* d_in, const int* in_sizes, int n_in,
                              void* d_out, int out_size, void* d_ws, size_t ws_size,
                              hipStream_t stream) {
    const float* n_feat = (const float*)d_in[0];
    const int*   src    = (const int*)d_in[1];
    const int*   dst    = (const int*)d_in[2];
    const int*   gid    = (const int*)d_in[3];
    const float* W1     = (const float*)d_in[4];
    const float* b1     = (const float*)d_in[5];
    const float* W2     = (const float*)d_in[6];
    const float* b2     = (const float*)d_in[7];
    const float* gamma  = (const float*)d_in[8];
    const float* beta   = (const float*)d_in[9];
    const float* fc1_w  = (const float*)d_in[10];
    const float* fc1_b  = (const float*)d_in[11];
    const float* fc2_w  = (const float*)d_in[12];
    const float* fc2_b  = (const float*)d_in[13];

    char* wsb = (char*)d_ws;
    size_t off = 0;
    auto alloc = [&](size_t bytes) -> void* {
        void* p = wsb + off;
        off += (bytes + 255) & ~(size_t)255;
        return p;
    };
    int*   cnt_in  = (int*)alloc((size_t)N_NODES * 4);
    int*   row_ptr = (int*)alloc((size_t)(N_NODES + 1) * 4);
    int*   e_src   = (int*)alloc((size_t)E_SRC_CAP * 4);
    float* inv_out = (float*)alloc((size_t)N_NODES * 4);
    float* inv_in  = (float*)alloc((size_t)N_NODES * 4);
    // ybuf doubles as: partial histograms (2*HB*HWORDS u32 = 16 MB), then bf16 Y incl. dummy row
    void*  ybuf    = alloc((size_t)2 * HB * HWORDS * 4);
    float* X       = (float*)alloc((size_t)N_NODES * HID * 4);
    unsigned short* Wp = (unsigned short*)alloc((size_t)2 * 32 * 64 * 8 * 2);  // 64 KB packed W1+W2
    float* scale   = (float*)alloc(HID * 4);
    float* shift   = (float*)alloc(HID * 4);
    float* H       = (float*)alloc((size_t)N_GRAPHS * HID * 4);
    int*   bsum    = (int*)alloc((size_t)SCAN_B * 4);
    int*   boff    = (int*)alloc((size_t)SCAN_B * 4);

    unsigned int*   part = (unsigned int*)ybuf;
    __hip_bfloat16* Y    = (__hip_bfloat16*)ybuf;  // (N_NODES+1) x HID bf16 = 12.8 MB + 256 B

    float* emb_out = (float*)d_out;                // [128,128]
    float* lsm_out = emb_out + N_GRAPHS * HID;     // [128,10]

    hipMemsetAsync(emb_out, 0, (size_t)N_GRAPHS * HID * 4, stream);

    hist_part_kernel<<<2 * HB, 1024, 0, stream>>>(src, dst, part);
    wpack_kernel<<<64, 64, 0, stream>>>(W1, W2, Wp);
    hist_reduce_kernel<<<(HWORDS + 255) / 256, 256, 0, stream>>>(part, cnt_in, inv_out, inv_in);
    scan_sum_kernel<<<N_SCAN_BLOCKS, SCAN_B, 0, stream>>>(cnt_in, bsum);
    scan_bsum_kernel<<<1, SCAN_B, 0, stream>>>(bsum, boff);
    scan_write_kernel<<<N_SCAN_BLOCKS, SCAN_B, 0, stream>>>(cnt_in, boff, row_ptr);
    csr_fill_kernel<<<HB, 1024, 0, stream>>>(src, dst, part, row_ptr, e_src);
    fill_pad_kernel<<<(N_NODES + 255) / 256, 256, 0, stream>>>(row_ptr, cnt_in, e_src);

    // layer 1 (MFMA bf16)
    matmul_kernel<<<(N_NODES + 64) / 64, 256, 0, stream>>>(n_feat, inv_out, Wp, Y);
    agg_kernel<<<(N_NODES + 3) / 4, 256, 0, stream>>>(Y, e_src, row_ptr, inv_in, b1, X);
    // layer 2
    matmul_kernel<<<(N_NODES + 64) / 64, 256, 0, stream>>>(X, inv_out, Wp + (size_t)32 * 64 * 8, Y);
    agg_kernel<<<(N_NODES + 3) / 4, 256, 0, stream>>>(Y, e_src, row_ptr, inv_in, b2, X);

    // pooling -> embedding output
    pool_kernel<<<N_POOL_BLOCKS, 64, 0, stream>>>(X, gid, emb_out);
    // head
    bnstats_kernel<<<1, HID, 0, stream>>>(emb_out, gamma, beta, scale, shift);
    fc1_kernel<<<N_GRAPHS, HID, 0, stream>>>(emb_out, scale, shift, fc1_w, fc1_b, H);
    head_kernel<<<N_GRAPHS, 64, 0, stream>>>(H, fc2_w, fc2_b, lsm_out);
}

// Round 9
// 253.369 us; speedup vs baseline: 2.5390x; 1.0314x over previous
//
#include <hip/hip_runtime.h>
#include <hip/hip_bf16.h>
#include <math.h>

#define N_NODES 50000
#define N_EDGES 800000
#define HID 128
#define N_GRAPHS 128
#define OUTC 10
#define BN_EPS 1e-5f

#define SCAN_B 256
#define N_SCAN_BLOCKS ((N_NODES + SCAN_B - 1) / SCAN_B)  // 196

#define POOL_CHUNK 32
#define N_POOL_BLOCKS ((N_NODES + POOL_CHUNK - 1) / POOL_CHUNK)  // 1563

#define HB 80                 // histogram blocks per index array
#define HWORDS (N_NODES / 2)  // 25000 packed u32 words (2 x u16 bins)
#define HR_B 128              // hist_reduce block: 128 words = 256 nodes = one scan chunk
#define HR_BLOCKS ((HWORDS + HR_B - 1) / HR_B)  // 196 == N_SCAN_BLOCKS

#define EPAD 8                // CSR row padding (edges), multiple of 8 for guard-free inner loop
#define E_SRC_CAP (N_EDGES + N_NODES * EPAD)  // worst-case padded edge slots

#define LDA 136               // LDS row stride (ushorts): 272 B = 17*16B -> aligned b128, 2-way banks

typedef short short8 __attribute__((ext_vector_type(8)));
typedef float floatx4 __attribute__((ext_vector_type(4)));

template <typename T, typename F>
__device__ inline T bitcast(F f) {
    union { F a; T b; } u;
    u.a = f;
    return u.b;
}

// ---------------- LDS partial histograms (no global atomics) + W-pack tail block ----------
// blocks [0,HB): histogram src; [HB,2HB): histogram dst; block 2HB: pack W1/W2 B-fragments.
__global__ __launch_bounds__(1024) void hist_part_kernel(const int* __restrict__ src,
                                                         const int* __restrict__ dst,
                                                         unsigned int* __restrict__ part,
                                                         const float* __restrict__ W1,
                                                         const float* __restrict__ W2,
                                                         unsigned short* __restrict__ Wp) {
    if (blockIdx.x == 2 * HB) {
        // pack W into MFMA B-frag order: lane holds B[k=quad*8+j][n=lane&15], j in [0,8)
        for (int q = threadIdx.x; q < 4096; q += 1024) {  // 2 mats x 32 tiles x 64 lanes
            int wi = q >> 11;
            const float* __restrict__ W = wi ? W2 : W1;
            int t2 = q & 2047;
            int tile = t2 >> 6, lane = t2 & 63;
            int kc = tile >> 3, nt = tile & 7;
            int n = lane & 15, quad = lane >> 4;
            unsigned short v[8];
#pragma unroll
            for (int j = 0; j < 8; j++) {
                int k = kc * 32 + quad * 8 + j;
                v[j] = __hip_bfloat16_raw(__float2bfloat16(W[k * HID + nt * 16 + n])).x;
            }
            *(uint4*)&Wp[(size_t)q * 8] = *(uint4*)v;
        }
        return;
    }
    __shared__ unsigned int h[HWORDS];  // 100 KB
    for (int i = threadIdx.x; i < HWORDS; i += 1024) h[i] = 0;
    __syncthreads();
    int half = (blockIdx.x >= HB) ? 1 : 0;
    const int* __restrict__ idx = half ? dst : src;
    int b = blockIdx.x - half * HB;
    for (int e = b * 1024 + threadIdx.x; e < N_EDGES; e += HB * 1024) {
        int v = idx[e];
        atomicAdd(&h[v >> 1], 1u << ((v & 1) << 4));  // LDS atomic, CU-local
    }
    __syncthreads();
    unsigned int* __restrict__ out = part + (size_t)blockIdx.x * HWORDS;
    for (int i = threadIdx.x; i < HWORDS; i += 1024) out[i] = h[i];
}

// Sum partials -> cnt_in / inv_out / inv_in; convert dst half of `part` in place to
// per-(block,node) exclusive prefixes; ALSO emit per-256-node-chunk padded sums (scan phase 1).
__global__ __launch_bounds__(HR_B) void hist_reduce_kernel(unsigned int* __restrict__ part,
                                                           int* __restrict__ cnt_in,
                                                           float* __restrict__ inv_out,
                                                           float* __restrict__ inv_in,
                                                           int* __restrict__ bsum) {
    int w = blockIdx.x * HR_B + threadIdx.x;
    int padsum = 0;
    if (w < HWORDS) {
        unsigned int s = 0, d = 0;
        for (int b = 0; b < HB; b++) {
            s += part[(size_t)b * HWORDS + w];
            unsigned int c = part[(size_t)(b + HB) * HWORDS + w];
            part[(size_t)(b + HB) * HWORDS + w] = d;  // exclusive prefix over blocks
            d += c;
        }
        int i0 = w * 2, i1 = i0 + 1;
        int so0 = (int)(s & 0xFFFFu), so1 = (int)(s >> 16);
        int di0 = (int)(d & 0xFFFFu), di1 = (int)(d >> 16);
        cnt_in[i0] = di0;
        cnt_in[i1] = di1;
        inv_out[i0] = rsqrtf(fmaxf((float)so0, 1.0f));
        inv_out[i1] = rsqrtf(fmaxf((float)so1, 1.0f));
        inv_in[i0] = rsqrtf(fmaxf((float)di0, 1.0f));
        inv_in[i1] = rsqrtf(fmaxf((float)di1, 1.0f));
        padsum = ((di0 + EPAD - 1) & ~(EPAD - 1)) + ((di1 + EPAD - 1) & ~(EPAD - 1));
    }
    __shared__ int red[HR_B];
    red[threadIdx.x] = padsum;
    __syncthreads();
    for (int o = HR_B / 2; o > 0; o >>= 1) {
        if (threadIdx.x < o) red[threadIdx.x] += red[threadIdx.x + o];
        __syncthreads();
    }
    if (threadIdx.x == 0) bsum[blockIdx.x] = red[0];
}

// ---------------- scan phase 2: single block scans chunk sums -> exclusive offsets ----------
__global__ void scan_bsum_kernel(const int* __restrict__ bsum, int* __restrict__ boff) {
    __shared__ int part[SCAN_B];
    int t = threadIdx.x;
    int v = (t < N_SCAN_BLOCKS) ? bsum[t] : 0;
    part[t] = v;
    __syncthreads();
    for (int off = 1; off < SCAN_B; off <<= 1) {
        int u = (t >= off) ? part[t - off] : 0;
        __syncthreads();
        part[t] += u;
        __syncthreads();
    }
    boff[t] = part[t] - v;
}

// ---------------- scan phase 3: row_ptr write + pad-slot fill (dummy row N_NODES) ----------
__global__ void scan_write_kernel(const int* __restrict__ cnt, const int* __restrict__ boff,
                                  int* __restrict__ row_ptr, int* __restrict__ edge_src) {
    __shared__ int part[SCAN_B];
    int t = threadIdx.x;
    int i = blockIdx.x * SCAN_B + t;
    int raw = (i < N_NODES) ? cnt[i] : 0;
    int v = (raw + EPAD - 1) & ~(EPAD - 1);
    part[t] = v;
    __syncthreads();
    for (int off = 1; off < SCAN_B; off <<= 1) {
        int u = (t >= off) ? part[t - off] : 0;
        __syncthreads();
        part[t] += u;
        __syncthreads();
    }
    if (i < N_NODES) {
        int ex = part[t] - v + boff[blockIdx.x];
        row_ptr[i] = ex;
        for (int p = ex + raw; p < ex + v; p++) edge_src[p] = N_NODES;  // pad slots
        if (i == N_NODES - 1) row_ptr[N_NODES] = ex + v;  // padded total
    }
}

// ---------------- CSR fill, atomic-free (disjoint from pad slots) ----------------
__global__ __launch_bounds__(1024) void csr_fill_kernel(const int* __restrict__ src,
                                                        const int* __restrict__ dst,
                                                        const unsigned int* __restrict__ part,
                                                        const int* __restrict__ row_ptr,
                                                        int* __restrict__ edge_src) {
    __shared__ unsigned int loc[HWORDS];  // 100 KB: packed u16 running intra-bucket slots
    int b = blockIdx.x;
    const unsigned int* __restrict__ off = part + (size_t)(b + HB) * HWORDS;
    for (int i = threadIdx.x; i < HWORDS; i += 1024) loc[i] = off[i];
    __syncthreads();
    for (int e = b * 1024 + threadIdx.x; e < N_EDGES; e += HB * 1024) {
        int d = dst[e];
        unsigned int old = atomicAdd(&loc[d >> 1], 1u << ((d & 1) << 4));  // LDS atomic
        int local = (d & 1) ? (int)(old >> 16) : (int)(old & 0xFFFFu);
        edge_src[row_ptr[d] + local] = src[e];  // plain scattered store
    }
}

// ---------------- Y[r][:] = bf16( (scale[r]*X[r][:]) @ W )  via MFMA bf16 ----------------
// block: 64 rows x 128 cols, 4 waves x (16 rows x 128 cols); emits dummy zero row N_NODES.
__global__ __launch_bounds__(256) void matmul_kernel(const float* __restrict__ X,
                                                     const float* __restrict__ scale,
                                                     const unsigned short* __restrict__ Wp,
                                                     __hip_bfloat16* __restrict__ Y) {
    __shared__ unsigned short xs[64 * LDA];  // 17 KB bf16, padded rows
    int tid = threadIdx.x;
    int row0 = blockIdx.x * 64;

    // stage 64x128 fp32 -> scaled bf16 LDS (coalesced float4 loads)
    for (int j = 0; j < 8; j++) {
        int idx4 = j * 256 + tid;          // float4 index in 64x128 tile
        int r = idx4 >> 5;                 // local row
        int col = (idx4 & 31) * 4;
        int rg = row0 + r;
        float4 v = make_float4(0.f, 0.f, 0.f, 0.f);
        if (rg < N_NODES) {
            v = *(const float4*)&X[(size_t)rg * HID + col];
            float sc = scale[rg];
            v.x *= sc; v.y *= sc; v.z *= sc; v.w *= sc;
        }
        unsigned short o[4];
        o[0] = __hip_bfloat16_raw(__float2bfloat16(v.x)).x;
        o[1] = __hip_bfloat16_raw(__float2bfloat16(v.y)).x;
        o[2] = __hip_bfloat16_raw(__float2bfloat16(v.z)).x;
        o[3] = __hip_bfloat16_raw(__float2bfloat16(v.w)).x;
        *(ushort4*)&xs[r * LDA + col] = *(ushort4*)o;
    }
    __syncthreads();

    int wave = tid >> 6, lane = tid & 63;
    int m = lane & 15, quad = lane >> 4;
    int rowl = wave * 16;  // wave's 16-row slice within tile

    // A frags: a[kc] = A[m][kc*32 + quad*8 .. +8]
    short8 a[4];
#pragma unroll
    for (int kc = 0; kc < 4; kc++)
        a[kc] = bitcast<short8>(*(const uint4*)&xs[(rowl + m) * LDA + kc * 32 + quad * 8]);

    floatx4 acc[8];
#pragma unroll
    for (int nt = 0; nt < 8; nt++) acc[nt] = (floatx4){0.f, 0.f, 0.f, 0.f};

#pragma unroll
    for (int nt = 0; nt < 8; nt++) {
#pragma unroll
        for (int kc = 0; kc < 4; kc++) {
            short8 bfr = bitcast<short8>(
                *(const uint4*)&Wp[((size_t)(kc * 8 + nt) * 64 + lane) * 8]);
            acc[nt] = __builtin_amdgcn_mfma_f32_16x16x32_bf16(a[kc], bfr, acc[nt], 0, 0, 0);
        }
    }

    // C/D layout: col = lane&15, row = quad*4 + reg  [verified m89]
#pragma unroll
    for (int nt = 0; nt < 8; nt++) {
#pragma unroll
        for (int i = 0; i < 4; i++) {
            int rg = row0 + rowl + quad * 4 + i;
            if (rg < N_NODES + 1) {
                Y[(size_t)rg * HID + nt * 16 + m] = __float2bfloat16(acc[nt][i]);
            }
        }
    }
}

// ---------------- CSR gather-accumulate over bf16 Y (fp32 accumulate) ----------------
__global__ __launch_bounds__(256) void agg_kernel(const __hip_bfloat16* __restrict__ Y,
                                                  const int* __restrict__ edge_src,
                                                  const int* __restrict__ row_ptr,
                                                  const float* __restrict__ inv_in,
                                                  const float* __restrict__ bias,
                                                  float* __restrict__ Xout) {
    const uint4* __restrict__ Yq = (const uint4*)Y;  // 8 bf16 per uint4
    int wave = threadIdx.x >> 6;
    int lane = threadIdx.x & 63;
    int n = blockIdx.x * 4 + wave;
    if (n >= N_NODES) return;
    int beg = row_ptr[n], end = row_ptr[n + 1];  // length multiple of 8
    int esub = lane >> 4;   // which of 4 concurrent edges
    int f16  = lane & 15;   // feature quad: feats f16*8 .. f16*8+7
    float acc[8] = {};
    for (int base = beg; base < end; base += 64) {
        int mm = min(64, end - base);  // multiple of 8
        int idx = (lane < mm) ? edge_src[base + lane] : N_NODES;
        for (int j = 0; j < mm; j += 8) {
            int s0 = __shfl(idx, j + esub);
            int s1 = __shfl(idx, j + 4 + esub);
            uint4 u0 = Yq[s0 * (HID / 8) + f16];
            uint4 u1 = Yq[s1 * (HID / 8) + f16];
            acc[0] += __uint_as_float(u0.x << 16); acc[1] += __uint_as_float(u0.x & 0xFFFF0000u);
            acc[2] += __uint_as_float(u0.y << 16); acc[3] += __uint_as_float(u0.y & 0xFFFF0000u);
            acc[4] += __uint_as_float(u0.z << 16); acc[5] += __uint_as_float(u0.z & 0xFFFF0000u);
            acc[6] += __uint_as_float(u0.w << 16); acc[7] += __uint_as_float(u0.w & 0xFFFF0000u);
            acc[0] += __uint_as_float(u1.x << 16); acc[1] += __uint_as_float(u1.x & 0xFFFF0000u);
            acc[2] += __uint_as_float(u1.y << 16); acc[3] += __uint_as_float(u1.y & 0xFFFF0000u);
            acc[4] += __uint_as_float(u1.z << 16); acc[5] += __uint_as_float(u1.z & 0xFFFF0000u);
            acc[6] += __uint_as_float(u1.w << 16); acc[7] += __uint_as_float(u1.w & 0xFFFF0000u);
        }
    }
#pragma unroll
    for (int i = 0; i < 8; i++) {
        acc[i] += __shfl_xor(acc[i], 16);
        acc[i] += __shfl_xor(acc[i], 32);
    }
    if (lane < 16) {
        float si = inv_in[n];
        int f0 = f16 * 8;
        float4 b0 = *(const float4*)&bias[f0];
        float4 b1 = *(const float4*)&bias[f0 + 4];
        float4 o0, o1;
        o0.x = fmaxf(acc[0] * si + b0.x, 0.f);
        o0.y = fmaxf(acc[1] * si + b0.y, 0.f);
        o0.z = fmaxf(acc[2] * si + b0.z, 0.f);
        o0.w = fmaxf(acc[3] * si + b0.w, 0.f);
        o1.x = fmaxf(acc[4] * si + b1.x, 0.f);
        o1.y = fmaxf(acc[5] * si + b1.y, 0.f);
        o1.z = fmaxf(acc[6] * si + b1.z, 0.f);
        o1.w = fmaxf(acc[7] * si + b1.w, 0.f);
        *(float4*)&Xout[(size_t)n * HID + f0] = o0;
        *(float4*)&Xout[(size_t)n * HID + f0 + 4] = o1;
    }
}

// ---------------- SumPooling: chunked segment-sum over sorted gid ----------------
__global__ __launch_bounds__(64) void pool_kernel(const float* __restrict__ X,
                                                  const int* __restrict__ gid,
                                                  float* __restrict__ emb) {
    int lane = threadIdx.x;
    int n0 = blockIdx.x * POOL_CHUNK;
    int n1 = min(n0 + POOL_CHUNK, N_NODES);
    if (n0 >= N_NODES) return;
    int g_cur = gid[n0];
    float ax = 0.f, ay = 0.f;
    for (int n = n0; n < n1; n++) {
        int g = gid[n];
        if (g != g_cur) {
            atomicAdd(&emb[g_cur * HID + lane * 2], ax);
            atomicAdd(&emb[g_cur * HID + lane * 2 + 1], ay);
            ax = 0.f; ay = 0.f;
            g_cur = g;
        }
        float2 v = *(const float2*)&X[(size_t)n * HID + lane * 2];
        ax += v.x;
        ay += v.y;
    }
    atomicAdd(&emb[g_cur * HID + lane * 2], ax);
    atomicAdd(&emb[g_cur * HID + lane * 2 + 1], ay);
}

// ---------------- fused BN-stats + fc1 + fc2 + log_softmax ----------------
// 128 blocks x 128 threads; each block redundantly computes BN stats (L2-hot 64 KB).
__global__ __launch_bounds__(128) void head_fused_kernel(const float* __restrict__ emb,
                                                         const float* __restrict__ gamma,
                                                         const float* __restrict__ beta,
                                                         const float* __restrict__ fc1_w,
                                                         const float* __restrict__ fc1_b,
                                                         const float* __restrict__ fc2_w,
                                                         const float* __restrict__ fc2_b,
                                                         float* __restrict__ out) {
    int r = blockIdx.x, f = threadIdx.x;
    float s = 0.f;
    for (int row = 0; row < N_GRAPHS; row++) s += emb[row * HID + f];
    float mu = s * (1.f / N_GRAPHS);
    float v = 0.f;
    for (int row = 0; row < N_GRAPHS; row++) {
        float d = emb[row * HID + f] - mu;
        v += d * d;
    }
    v *= (1.f / N_GRAPHS);
    float sc = gamma[f] * rsqrtf(v + BN_EPS);
    float sh = beta[f] - mu * sc;

    __shared__ float xr[HID];
    xr[f] = emb[r * HID + f] * sc + sh;
    __syncthreads();
    float acc = fc1_b[f];
    for (int k = 0; k < HID; k++) acc += xr[k] * fc1_w[k * HID + f];
    __shared__ float hr[HID];
    hr[f] = fmaxf(acc, 0.f);
    __syncthreads();

    __shared__ float logits[OUTC];
    __shared__ float mstat[2];
    if (f < OUTC) {
        float a = fc2_b[f];
        for (int k = 0; k < HID; k++) a += hr[k] * fc2_w[k * OUTC + f];
        logits[f] = a;
    }
    __syncthreads();
    if (f == 0) {
        float m = logits[0];
        for (int o = 1; o < OUTC; o++) m = fmaxf(m, logits[o]);
        float sum = 0.f;
        for (int o = 0; o < OUTC; o++) sum += expf(logits[o] - m);
        mstat[0] = m;
        mstat[1] = logf(sum);
    }
    __syncthreads();
    if (f < OUTC) out[r * OUTC + f] = logits[f] - mstat[0] - mstat[1];
}

extern "C" void kernel_launch(void* const* d_in, const int* in_sizes, int n_in,
                              void* d_out, int out_size, void* d_ws, size_t ws_size,
                              hipStream_t stream) {
    const float* n_feat = (const float*)d_in[0];
    const int*   src    = (const int*)d_in[1];
    const int*   dst    = (const int*)d_in[2];
    const int*   gid    = (const int*)d_in[3];
    const float* W1     = (const float*)d_in[4];
    const float* b1     = (const float*)d_in[5];
    const float* W2     = (const float*)d_in[6];
    const float* b2     = (const float*)d_in[7];
    const float* gamma  = (const float*)d_in[8];
    const float* beta   = (const float*)d_in[9];
    const float* fc1_w  = (const float*)d_in[10];
    const float* fc1_b  = (const float*)d_in[11];
    const float* fc2_w  = (const float*)d_in[12];
    const float* fc2_b  = (const float*)d_in[13];

    char* wsb = (char*)d_ws;
    size_t off = 0;
    auto alloc = [&](size_t bytes) -> void* {
        void* p = wsb + off;
        off += (bytes + 255) & ~(size_t)255;
        return p;
    };
    int*   cnt_in  = (int*)alloc((size_t)N_NODES * 4);
    int*   row_ptr = (int*)alloc((size_t)(N_NODES + 1) * 4);
    int*   e_src   = (int*)alloc((size_t)E_SRC_CAP * 4);
    float* inv_out = (float*)alloc((size_t)N_NODES * 4);
    float* inv_in  = (float*)alloc((size_t)N_NODES * 4);
    // ybuf doubles as: partial histograms (2*HB*HWORDS u32 = 16 MB), then bf16 Y incl. dummy row
    void*  ybuf    = alloc((size_t)2 * HB * HWORDS * 4);
    float* X       = (float*)alloc((size_t)N_NODES * HID * 4);
    unsigned short* Wp = (unsigned short*)alloc((size_t)2 * 32 * 64 * 8 * 2);  // 64 KB packed W1+W2
    int*   bsum    = (int*)alloc((size_t)SCAN_B * 4);
    int*   boff    = (int*)alloc((size_t)SCAN_B * 4);

    unsigned int*   part = (unsigned int*)ybuf;
    __hip_bfloat16* Y    = (__hip_bfloat16*)ybuf;  // (N_NODES+1) x HID bf16 = 12.8 MB + 256 B

    float* emb_out = (float*)d_out;                // [128,128]
    float* lsm_out = emb_out + N_GRAPHS * HID;     // [128,10]

    hipMemsetAsync(emb_out, 0, (size_t)N_GRAPHS * HID * 4, stream);

    hist_part_kernel<<<2 * HB + 1, 1024, 0, stream>>>(src, dst, part, W1, W2, Wp);
    hist_reduce_kernel<<<HR_BLOCKS, HR_B, 0, stream>>>(part, cnt_in, inv_out, inv_in, bsum);
    scan_bsum_kernel<<<1, SCAN_B, 0, stream>>>(bsum, boff);
    scan_write_kernel<<<N_SCAN_BLOCKS, SCAN_B, 0, stream>>>(cnt_in, boff, row_ptr, e_src);
    csr_fill_kernel<<<HB, 1024, 0, stream>>>(src, dst, part, row_ptr, e_src);

    // layer 1 (MFMA bf16)
    matmul_kernel<<<(N_NODES + 64) / 64, 256, 0, stream>>>(n_feat, inv_out, Wp, Y);
    agg_kernel<<<(N_NODES + 3) / 4, 256, 0, stream>>>(Y, e_src, row_ptr, inv_in, b1, X);
    // layer 2
    matmul_kernel<<<(N_NODES + 64) / 64, 256, 0, stream>>>(X, inv_out, Wp + (size_t)32 * 64 * 8, Y);
    agg_kernel<<<(N_NODES + 3) / 4, 256, 0, stream>>>(Y, e_src, row_ptr, inv_in, b2, X);

    // pooling -> embedding output
    pool_kernel<<<N_POOL_BLOCKS, 64, 0, stream>>>(X, gid, emb_out);
    // fused head
    head_fused_kernel<<<N_GRAPHS, HID, 0, stream>>>(emb_out, gamma, beta, fc1_w, fc1_b,
                                                    fc2_w, fc2_b, lsm_out);
}